// Round 15
// baseline (343.746 us; speedup 1.0000x reference)
//
#include <hip/hip_runtime.h>
#include <math.h>

typedef __attribute__((ext_vector_type(8))) short   short8;
typedef __attribute__((ext_vector_type(4))) short   short4v;
typedef __attribute__((ext_vector_type(8))) __bf16  bf16x8;
typedef __attribute__((ext_vector_type(4))) float   f32x4;
typedef __attribute__((ext_vector_type(16))) float  f32x16;
typedef unsigned short u16;

#define DIMD 1024
#define NHEAD 16
#define HD 64
#define FFD 4096
#define BB 2
#define SSEQ 2048
#define NSPLIT 2
#define KVSPAN (SSEQ / NSPLIT)
#define NROWS (BB * NHEAD * SSEQ)
#define NEGF -3.4028235e38f

__device__ __forceinline__ u16 f2bf(float f){
  unsigned u = __float_as_uint(f);
  u += 0x7FFFu + ((u >> 16) & 1u);
  return (u16)(u >> 16);
}
__device__ __forceinline__ float bf2f(u16 v){
  return __uint_as_float(((unsigned)v) << 16);
}
__device__ __forceinline__ void gload16(const u16* g, u16* l){
  __builtin_amdgcn_global_load_lds((const __attribute__((address_space(1))) void*)g,
                                   (__attribute__((address_space(3))) void*)l, 16, 0, 0);
}

// ---------------- mask dtype discriminator + normalizer (u8 0/1) ----------------
__global__ void normalize_mask(const unsigned char* __restrict__ m, unsigned char* __restrict__ outm){
  __shared__ int any;
  if (threadIdx.x == 0) any = 0;
  __syncthreads();
  int bad = 0;
  for (int i = threadIdx.x; i < BB * SSEQ; i += 1024)
    if ((i & 3) && m[i]) bad = 1;
  if (bad) atomicOr(&any, 1);
  __syncthreads();
  bool is_i32 = (any == 0);
  if (is_i32){
    const int* mi = (const int*)m;
    for (int k = threadIdx.x; k < BB * SSEQ; k += 1024)
      outm[k] = (unsigned char)(mi[k] != 0);
  } else {
    for (int k = threadIdx.x; k < BB * SSEQ; k += 1024)
      outm[k] = m[k] ? 1 : 0;
  }
}

// ---------------- weight transpose + fp32->bf16 ----------------
__global__ void transpose_to_bf16(const float* __restrict__ W, u16* __restrict__ Wt, int K, int N){
  __shared__ float tile[32][33];
  int n0 = blockIdx.x * 32, k0 = blockIdx.y * 32;
  int tx = threadIdx.x, ty = threadIdx.y;   // 32 x 8
  #pragma unroll
  for (int i = 0; i < 32; i += 8)
    tile[ty + i][tx] = W[(size_t)(k0 + ty + i) * N + n0 + tx];
  __syncthreads();
  #pragma unroll
  for (int i = 0; i < 32; i += 8)
    Wt[(size_t)(n0 + ty + i) * K + k0 + tx] = f2bf(tile[tx][ty + i]);
}

// fused 4x square (1024x1024) transpose: z selects matrix
__global__ void transpose4_to_bf16(const float* __restrict__ Wq, const float* __restrict__ Wk,
                                   const float* __restrict__ Wv, const float* __restrict__ Wo,
                                   u16* __restrict__ Tqkv, u16* __restrict__ To){
  __shared__ float tile[32][33];
  const float* W;
  u16* T;
  switch (blockIdx.z){
    case 0: W = Wq; T = Tqkv;                        break;
    case 1: W = Wk; T = Tqkv + (size_t)1024*1024;    break;
    case 2: W = Wv; T = Tqkv + (size_t)2048*1024;    break;
    default: W = Wo; T = To;                         break;
  }
  int n0 = blockIdx.x * 32, k0 = blockIdx.y * 32;
  int tx = threadIdx.x, ty = threadIdx.y;
  #pragma unroll
  for (int i = 0; i < 32; i += 8)
    tile[ty + i][tx] = W[(size_t)(k0 + ty + i) * 1024 + n0 + tx];
  __syncthreads();
  #pragma unroll
  for (int i = 0; i < 32; i += 8)
    T[(size_t)(n0 + ty + i) * 1024 + k0 + tx] = f2bf(tile[tx][ty + i]);
}

// ---------------- V global transpose: qkv V-block -> vt[b,h][dcol][S] ----------------
__global__ void vtrans(const u16* __restrict__ qkv, u16* __restrict__ vt){
  __shared__ u16 tile[32][33];
  int s0 = blockIdx.x * 32, d0 = blockIdx.y * 32;
  int bh = blockIdx.z;              // b*NHEAD + h
  int b = bh >> 4, h = bh & 15;
  int tx = threadIdx.x, ty = threadIdx.y;
  const u16* src = qkv + (size_t)(b * SSEQ) * 3072 + 2048 + h * HD + d0;
  #pragma unroll
  for (int i = 0; i < 32; i += 8)
    tile[ty + i][tx] = src[(size_t)(s0 + ty + i) * 3072 + tx];
  __syncthreads();
  u16* dst = vt + ((size_t)bh * HD + d0) * SSEQ + s0;
  #pragma unroll
  for (int i = 0; i < 32; i += 8)
    dst[(size_t)(ty + i) * SSEQ + tx] = tile[tx][ty + i];
}

// ---------------- RMSNorm: fp32 in -> bf16 out ----------------
__global__ __launch_bounds__(256) void rmsnorm_k(const float* __restrict__ x, const float* __restrict__ g,
                                                 u16* __restrict__ out, int D){
  int row = blockIdx.x;
  const float* xr = x + (size_t)row * D;
  float ss = 0.f;
  for (int i = threadIdx.x * 4; i < D; i += 1024){
    float4 v = *(const float4*)&xr[i];
    ss += v.x*v.x + v.y*v.y + v.z*v.z + v.w*v.w;
  }
  #pragma unroll
  for (int o = 32; o > 0; o >>= 1) ss += __shfl_down(ss, o);
  __shared__ float red[4];
  if ((threadIdx.x & 63) == 0) red[threadIdx.x >> 6] = ss;
  __syncthreads();
  float tot = red[0] + red[1] + red[2] + red[3];
  float rs = rsqrtf(tot / (float)D + 1e-6f);
  for (int i = threadIdx.x * 4; i < D; i += 1024){
    float4 v  = *(const float4*)&xr[i];
    float4 gv = *(const float4*)&g[i];
    ushort4 o4;
    o4.x = f2bf(v.x * rs * gv.x);
    o4.y = f2bf(v.y * rs * gv.y);
    o4.z = f2bf(v.z * rs * gv.z);
    o4.w = f2bf(v.w * rs * gv.w);
    *(ushort4*)&out[(size_t)row * D + i] = o4;
  }
}

// ---- bijective XCD swizzle for grids with (gridX*gridY) % 8 == 0 ----
__device__ __forceinline__ void xcd_swz(int& bx, int& by){
  int gx = gridDim.x, nwg = gx * gridDim.y;
  int flat = by * gx + bx;
  int q = nwg >> 3;
  flat = (flat & 7) * q + (flat >> 3);
  bx = flat % gx;
  by = flat / gx;
}

// ================= 8-phase-style 256x256 GEMM, BK=32, 3-deep pipeline =================
template<int EPI>
__global__ __launch_bounds__(512, 2) void gemm8p(const u16* __restrict__ A, const u16* __restrict__ Bt,
                                                 u16* __restrict__ outb, const float* __restrict__ bias,
                                                 int M, int N, int K){
  extern __shared__ u16 lds[];   // 3 * 16384 u16
  const int tid = threadIdx.x;
  const int lane = tid & 63, lr = lane >> 4, lc = lane & 15;
  const int wid = tid >> 6, wr = wid >> 2, wc = wid & 3;
  int bx = blockIdx.x, by = blockIdx.y;
  xcd_swz(bx, by);
  const int m0 = by * 256, n0 = bx * 256;
  const int NT = K >> 5;
  const int slot8 = ((lr ^ (lc & 3)) << 3);

  f32x4 acc[8][4];
  #pragma unroll
  for (int i = 0; i < 8; i++)
    #pragma unroll
    for (int j = 0; j < 4; j++) acc[i][j] = (f32x4){0.f,0.f,0.f,0.f};

  const int srow = tid >> 2;
  const int scg  = (tid & 3) ^ (srow & 3);

  auto stage = [&](int t, int buf, int rsel){
    int row = ((rsel & 1) << 7) + srow;
    const u16* src = ((rsel < 2) ? A + (size_t)(m0 + row) * K
                                 : Bt + (size_t)(n0 + row) * K) + t * 32 + scg * 8;
    u16* dst = lds + buf * 16384 + ((rsel & 2) << 12) + ((rsel & 1) << 12) + tid * 8;
    gload16(src, dst);
  };
  auto ldA = [&](int buf, int mi) -> bf16x8 {
    int ra = wr * 128 + mi * 16 + lc;
    return *(const bf16x8*)&lds[buf * 16384 + ra * 32 + slot8];
  };
  auto ldB = [&](int buf, int ni) -> bf16x8 {
    int rb = wc * 64 + ni * 16 + lc;
    return *(const bf16x8*)&lds[buf * 16384 + 8192 + rb * 32 + slot8];
  };

  #pragma unroll
  for (int rs = 0; rs < 4; rs++) stage(0, 0, rs);
  #pragma unroll
  for (int rs = 0; rs < 4; rs++) stage(1, 1, rs);
  asm volatile("s_waitcnt vmcnt(4)" ::: "memory");
  __builtin_amdgcn_s_barrier();

  int buf = 0;
  for (int t = 0; t < NT; t++){
    int sbuf = buf + 2; if (sbuf >= 3) sbuf -= 3;
    bool ds = (t + 2 < NT);
    bf16x8 a[4], b[4];
    #pragma unroll
    for (int mi = 0; mi < 4; mi++) a[mi] = ldA(buf, mi);
    #pragma unroll
    for (int ni = 0; ni < 4; ni++) b[ni] = ldB(buf, ni);
    if (ds){ stage(t + 2, sbuf, 0); stage(t + 2, sbuf, 1); }
    __builtin_amdgcn_s_barrier();
    __builtin_amdgcn_s_setprio(1);
    #pragma unroll
    for (int mi = 0; mi < 4; mi++)
      #pragma unroll
      for (int ni = 0; ni < 4; ni++)
        acc[mi][ni] = __builtin_amdgcn_mfma_f32_16x16x32_bf16(a[mi], b[ni], acc[mi][ni], 0, 0, 0);
    __builtin_amdgcn_s_setprio(0);
    __builtin_amdgcn_s_barrier();
    #pragma unroll
    for (int mi = 0; mi < 4; mi++) a[mi] = ldA(buf, mi + 4);
    if (ds){ stage(t + 2, sbuf, 2); stage(t + 2, sbuf, 3); }
    __builtin_amdgcn_s_barrier();
    __builtin_amdgcn_s_setprio(1);
    #pragma unroll
    for (int mi = 0; mi < 4; mi++)
      #pragma unroll
      for (int ni = 0; ni < 4; ni++)
        acc[mi + 4][ni] = __builtin_amdgcn_mfma_f32_16x16x32_bf16(a[mi], b[ni], acc[mi + 4][ni], 0, 0, 0);
    __builtin_amdgcn_s_setprio(0);
    if (t + 2 < NT)      { asm volatile("s_waitcnt vmcnt(4)" ::: "memory"); }
    else if (t + 1 < NT) { asm volatile("s_waitcnt vmcnt(0)" ::: "memory"); }
    __builtin_amdgcn_s_barrier();
    buf++; if (buf == 3) buf = 0;
  }

  #pragma unroll
  for (int mi = 0; mi < 8; mi++){
    #pragma unroll
    for (int ni = 0; ni < 4; ni++){
      int col = n0 + wc * 64 + ni * 16 + lc;
      #pragma unroll
      for (int r = 0; r < 4; r++){
        int row = m0 + wr * 128 + mi * 16 + lr * 4 + r;
        float v = acc[mi][ni][r];
        if (EPI == 2){
          v += bias[col];
          v = 0.5f * v * (1.f + erff(v * 0.70710678118654752f));
        }
        outb[(size_t)row * N + col] = f2bf(v);
      }
    }
  }
}

// ======== split-K variant: grid.z = K-chunk; writes bf16 partial [sk][M][N] ========
__global__ __launch_bounds__(512, 2) void gemm8p_sk(const u16* __restrict__ A, const u16* __restrict__ Bt,
                                                    u16* __restrict__ part,
                                                    int M, int N, int Kstride, int Klen){
  extern __shared__ u16 lds[];
  const int tid = threadIdx.x;
  const int lane = tid & 63, lr = lane >> 4, lc = lane & 15;
  const int wid = tid >> 6, wr = wid >> 2, wc = wid & 3;
  int bx = blockIdx.x, by = blockIdx.y;
  xcd_swz(bx, by);
  const int sk = blockIdx.z;
  const size_t koff = (size_t)sk * Klen;
  const int m0 = by * 256, n0 = bx * 256;
  const int NT = Klen >> 5;
  const int slot8 = ((lr ^ (lc & 3)) << 3);

  f32x4 acc[8][4];
  #pragma unroll
  for (int i = 0; i < 8; i++)
    #pragma unroll
    for (int j = 0; j < 4; j++) acc[i][j] = (f32x4){0.f,0.f,0.f,0.f};

  const int srow = tid >> 2;
  const int scg  = (tid & 3) ^ (srow & 3);

  auto stage = [&](int t, int buf, int rsel){
    int row = ((rsel & 1) << 7) + srow;
    const u16* src = ((rsel < 2) ? A + (size_t)(m0 + row) * Kstride
                                 : Bt + (size_t)(n0 + row) * Kstride) + koff + t * 32 + scg * 8;
    u16* dst = lds + buf * 16384 + ((rsel & 2) << 12) + ((rsel & 1) << 12) + tid * 8;
    gload16(src, dst);
  };
  auto ldA = [&](int buf, int mi) -> bf16x8 {
    int ra = wr * 128 + mi * 16 + lc;
    return *(const bf16x8*)&lds[buf * 16384 + ra * 32 + slot8];
  };
  auto ldB = [&](int buf, int ni) -> bf16x8 {
    int rb = wc * 64 + ni * 16 + lc;
    return *(const bf16x8*)&lds[buf * 16384 + 8192 + rb * 32 + slot8];
  };

  #pragma unroll
  for (int rs = 0; rs < 4; rs++) stage(0, 0, rs);
  #pragma unroll
  for (int rs = 0; rs < 4; rs++) stage(1, 1, rs);
  asm volatile("s_waitcnt vmcnt(4)" ::: "memory");
  __builtin_amdgcn_s_barrier();

  int buf = 0;
  for (int t = 0; t < NT; t++){
    int sbuf = buf + 2; if (sbuf >= 3) sbuf -= 3;
    bool ds = (t + 2 < NT);
    bf16x8 a[4], b[4];
    #pragma unroll
    for (int mi = 0; mi < 4; mi++) a[mi] = ldA(buf, mi);
    #pragma unroll
    for (int ni = 0; ni < 4; ni++) b[ni] = ldB(buf, ni);
    if (ds){ stage(t + 2, sbuf, 0); stage(t + 2, sbuf, 1); }
    __builtin_amdgcn_s_barrier();
    __builtin_amdgcn_s_setprio(1);
    #pragma unroll
    for (int mi = 0; mi < 4; mi++)
      #pragma unroll
      for (int ni = 0; ni < 4; ni++)
        acc[mi][ni] = __builtin_amdgcn_mfma_f32_16x16x32_bf16(a[mi], b[ni], acc[mi][ni], 0, 0, 0);
    __builtin_amdgcn_s_setprio(0);
    __builtin_amdgcn_s_barrier();
    #pragma unroll
    for (int mi = 0; mi < 4; mi++) a[mi] = ldA(buf, mi + 4);
    if (ds){ stage(t + 2, sbuf, 2); stage(t + 2, sbuf, 3); }
    __builtin_amdgcn_s_barrier();
    __builtin_amdgcn_s_setprio(1);
    #pragma unroll
    for (int mi = 0; mi < 4; mi++)
      #pragma unroll
      for (int ni = 0; ni < 4; ni++)
        acc[mi + 4][ni] = __builtin_amdgcn_mfma_f32_16x16x32_bf16(a[mi], b[ni], acc[mi + 4][ni], 0, 0, 0);
    __builtin_amdgcn_s_setprio(0);
    if (t + 2 < NT)      { asm volatile("s_waitcnt vmcnt(4)" ::: "memory"); }
    else if (t + 1 < NT) { asm volatile("s_waitcnt vmcnt(0)" ::: "memory"); }
    __builtin_amdgcn_s_barrier();
    buf++; if (buf == 3) buf = 0;
  }

  u16* po = part + (size_t)sk * M * N;
  #pragma unroll
  for (int mi = 0; mi < 8; mi++){
    #pragma unroll
    for (int ni = 0; ni < 4; ni++){
      int col = n0 + wc * 64 + ni * 16 + lc;
      #pragma unroll
      for (int r = 0; r < 4; r++){
        int row = m0 + wr * 128 + mi * 16 + lr * 4 + r;
        po[(size_t)row * N + col] = f2bf(acc[mi][ni][r]);
      }
    }
  }
}

// ---- O-proj merge + residual + fused RMSNorm2: writes x2 (fp32) AND h2 (bf16) ----
__global__ __launch_bounds__(256) void skmerge_rms(const u16* __restrict__ part, const float* __restrict__ resid,
                                                   const float* __restrict__ g2, float* __restrict__ x2,
                                                   u16* __restrict__ h2){
  size_t i = ((size_t)blockIdx.x * 256 + threadIdx.x) * 8;
  int col = (int)(i & (DIMD - 1));
  const size_t MN = (size_t)4096 * DIMD;
  short8 a0 = *(const short8*)&part[i];
  short8 a1 = *(const short8*)&part[MN + i];
  short8 a2 = *(const short8*)&part[2 * MN + i];
  short8 a3 = *(const short8*)&part[3 * MN + i];
  float4 xa = *(const float4*)&resid[i];
  float4 xb = *(const float4*)&resid[i + 4];
  float o[8];
  #pragma unroll
  for (int j = 0; j < 8; j++)
    o[j] = (bf2f((u16)a0[j]) + bf2f((u16)a1[j])) + (bf2f((u16)a2[j]) + bf2f((u16)a3[j]));
  o[0] += xa.x; o[1] += xa.y; o[2] += xa.z; o[3] += xa.w;
  o[4] += xb.x; o[5] += xb.y; o[6] += xb.z; o[7] += xb.w;
  *(float4*)&x2[i]     = (float4){o[0], o[1], o[2], o[3]};
  *(float4*)&x2[i + 4] = (float4){o[4], o[5], o[6], o[7]};

  float ss = 0.f;
  #pragma unroll
  for (int j = 0; j < 8; j++) ss += o[j] * o[j];
  #pragma unroll
  for (int off = 32; off > 0; off >>= 1) ss += __shfl_down(ss, off);
  __shared__ float red[4];
  if ((threadIdx.x & 63) == 0) red[threadIdx.x >> 6] = ss;
  __syncthreads();
  float tot = (threadIdx.x < 128) ? (red[0] + red[1]) : (red[2] + red[3]);
  float rs = rsqrtf(tot / (float)DIMD + 1e-6f);
  float4 ga = *(const float4*)&g2[col];
  float4 gb = *(const float4*)&g2[col + 4];
  ushort4 h0, h1;
  h0.x = f2bf(o[0] * rs * ga.x); h0.y = f2bf(o[1] * rs * ga.y);
  h0.z = f2bf(o[2] * rs * ga.z); h0.w = f2bf(o[3] * rs * ga.w);
  h1.x = f2bf(o[4] * rs * gb.x); h1.y = f2bf(o[5] * rs * gb.y);
  h1.z = f2bf(o[6] * rs * gb.z); h1.w = f2bf(o[7] * rs * gb.w);
  *(ushort4*)&h2[i]     = h0;
  *(ushort4*)&h2[i + 4] = h1;
}

// merge 4 bf16 partials + resid + bias -> fp32 out  (FFN2)
__global__ __launch_bounds__(256) void ffn2_merge(const u16* __restrict__ part, const float* __restrict__ x2,
                                                  const float* __restrict__ b2, float* __restrict__ out){
  size_t i = ((size_t)blockIdx.x * 256 + threadIdx.x) * 8;
  int col = (int)(i & (DIMD - 1));
  const size_t MN = (size_t)4096 * DIMD;
  short8 a0 = *(const short8*)&part[i];
  short8 a1 = *(const short8*)&part[MN + i];
  short8 a2 = *(const short8*)&part[2 * MN + i];
  short8 a3 = *(const short8*)&part[3 * MN + i];
  float r[8];
  #pragma unroll
  for (int j = 0; j < 8; j++)
    r[j] = (bf2f((u16)a0[j]) + bf2f((u16)a1[j])) + (bf2f((u16)a2[j]) + bf2f((u16)a3[j]));
  float4 xa = *(const float4*)&x2[i];
  float4 xb = *(const float4*)&x2[i + 4];
  float4 ba = *(const float4*)&b2[col];
  float4 bb = *(const float4*)&b2[col + 4];
  float4 o0 = {r[0] + xa.x + ba.x, r[1] + xa.y + ba.y, r[2] + xa.z + ba.z, r[3] + xa.w + ba.w};
  float4 o1 = {r[4] + xb.x + bb.x, r[5] + xb.y + bb.y, r[6] + xb.z + bb.z, r[7] + xb.w + bb.w};
  *(float4*)&out[i] = o0;
  *(float4*)&out[i + 4] = o1;
}

// ---------------- flash attention: 32x32 swapped QK^T + bias double-buffer ----------------
__global__ __launch_bounds__(256) void attn_part(const u16* __restrict__ qkv, const u16* __restrict__ vt,
                                                 const float* __restrict__ bias,
                                                 const unsigned char* __restrict__ mask,
                                                 u16* __restrict__ Opart, float* __restrict__ mp, float* __restrict__ lp){
  __shared__ u16 Ks [64 * 64];   // [key][d]   XOR-swizzled
  __shared__ u16 Vts[64 * 64];   // [d][key]   XOR-swizzled
  __shared__ u16 Ps [4 * 32 * 72]; // per-wave [q=32][key=64 (+pad)]

  const int tid = threadIdx.x;
  const int lane = tid & 63, hi = lane >> 5, lq = lane & 31;
  const int wq = tid >> 6;
  const int b  = blockIdx.x & 1;
  const int qb = blockIdx.x >> 1;
  const int h  = blockIdx.y;
  const int sp = blockIdx.z;
  const int qw = qb * 128 + wq * 32;
  const int kv_lo = sp * KVSPAN, kv_hi = kv_lo + KVSPAN;

  char* kls = (char*)Ks;
  char* vls = (char*)Vts;
  u16*  psw = Ps + wq * 32 * 72;

  bf16x8 qf[4];
  {
    const u16* qp = qkv + ((size_t)(b * SSEQ + qw + lq)) * 3072 + h * HD + hi * 8;
    #pragma unroll
    for (int dstep = 0; dstep < 4; dstep++) qf[dstep] = *(const bf16x8*)(qp + dstep * 16);
  }

  const u16* kbase = qkv + (size_t)b * SSEQ * 3072 + 1024 + h * HD;
  const u16* vbase = vt + (size_t)(b * NHEAD + h) * HD * SSEQ;
  const int c0 = tid, c1 = tid + 256;
  auto kaddr = [&](int kv0, int c){ return kbase + (size_t)(kv0 + (c >> 3)) * 3072 + (c & 7) * 8; };
  auto vaddr = [&](int kv0, int c){ return vbase + (size_t)(c >> 3) * SSEQ + kv0 + (c & 7) * 8; };
  auto sstore = [&](char* base, int c, short8 v){
    int byte = (c >> 3) * 128 + (c & 7) * 16;
    byte ^= ((c >> 3) & 7) << 4;
    *(short8*)(base + byte) = v;
  };

  const float* brow = bias + ((size_t)h * SSEQ + (qw + lq)) * SSEQ;
  const unsigned char* mbase = mask + b * SSEQ;
  float4 bvA[8]; unsigned mkA[8];
  auto bload = [&](int kv0, float4* bv, unsigned* mk){
    #pragma unroll
    for (int kg = 0; kg < 2; kg++)
      #pragma unroll
      for (int rq = 0; rq < 4; rq++){
        int base = kv0 + kg * 32 + 8 * rq + 4 * hi;
        bv[kg*4+rq] = *(const float4*)&brow[base];
        mk[kg*4+rq] = *(const unsigned*)&mbase[base];
      }
  };

  short8 kr0 = *(const short8*)kaddr(kv_lo, c0);
  short8 kr1 = *(const short8*)kaddr(kv_lo, c1);
  short8 vr0 = *(const short8*)vaddr(kv_lo, c0);
  short8 vr1 = *(const short8*)vaddr(kv_lo, c1);
  bload(kv_lo, bvA, mkA);   // prologue bias tile 0

  float mrow = NEGF, lsum = 0.f;
  f32x16 oacc[2];
  #pragma unroll
  for (int g = 0; g < 2; g++)
    #pragma unroll
    for (int r = 0; r < 16; r++) oacc[g][r] = 0.f;

  for (int kv0 = kv_lo; kv0 < kv_hi; kv0 += 64){
    int nxt = (kv0 + 64 < kv_hi) ? kv0 + 64 : kv_lo;

    __syncthreads();
    sstore(kls, c0, kr0); sstore(kls, c1, kr1);
    sstore(vls, c0, vr0); sstore(vls, c1, vr1);
    __syncthreads();

    // prefetch next K/V tile
    kr0 = *(const short8*)kaddr(nxt, c0);
    kr1 = *(const short8*)kaddr(nxt, c1);
    vr0 = *(const short8*)vaddr(nxt, c0);
    vr1 = *(const short8*)vaddr(nxt, c1);

    f32x16 acc[2];
    #pragma unroll
    for (int g = 0; g < 2; g++)
      #pragma unroll
      for (int r = 0; r < 16; r++) acc[g][r] = 0.f;
    __builtin_amdgcn_s_setprio(1);
    #pragma unroll
    for (int kg = 0; kg < 2; kg++){
      int row = kg * 32 + lq;
      #pragma unroll
      for (int dstep = 0; dstep < 4; dstep++){
        int byte = row * 128 + dstep * 32 + hi * 16;
        byte ^= (row & 7) << 4;
        bf16x8 kf = *(const bf16x8*)(kls + byte);
        acc[kg] = __builtin_amdgcn_mfma_f32_32x32x16_bf16(kf, qf[dstep], acc[kg], 0, 0, 0);
      }
    }
    __builtin_amdgcn_s_setprio(0);

    // ---- scores using THIS tile's (prefetched) bias; then immediately issue next tile's bias ----
    float p[2][16];
    float tm = NEGF;
    #pragma unroll
    for (int kg = 0; kg < 2; kg++)
      #pragma unroll
      for (int r = 0; r < 16; r++){
        int g = kg * 4 + (r >> 2);
        bool m = ((mkA[g] >> (8 * (r & 3))) & 0xffu) != 0;
        float v = acc[kg][r] * 0.125f + ((const float*)&bvA[g])[r & 3];
        v = m ? NEGF : v;
        p[kg][r] = v;
        tm = fmaxf(tm, v);
      }

    // issue bias/mask loads for next tile NOW -> full exp+PV+barrier+stage+QK of cover
    float4 bvB[8]; unsigned mkB[8];
    bload(nxt, bvB, mkB);

    tm = fmaxf(tm, __shfl_xor(tm, 32));

    if (__any(tm > mrow + 5.f)){
      float mnew = fmaxf(mrow, tm);
      float corr = __expf(mrow - mnew);
      lsum *= corr;
      mrow = mnew;
      #pragma unroll
      for (int r = 0; r < 16; r++){
        float cr = __shfl(corr, (r & 3) + 8 * (r >> 2) + 4 * hi);
        oacc[0][r] *= cr;
        oacc[1][r] *= cr;
      }
    }

    float psum = 0.f;
    #pragma unroll
    for (int kg = 0; kg < 2; kg++)
      #pragma unroll
      for (int r = 0; r < 16; r++){
        float sv = p[kg][r];
        float e = (sv < -1e30f) ? 0.f : __expf(sv - mrow);
        p[kg][r] = e;
        psum += e;
      }
    psum += __shfl_xor(psum, 32);
    lsum += psum;

    #pragma unroll
    for (int kg = 0; kg < 2; kg++)
      #pragma unroll
      for (int rq = 0; rq < 4; rq++){
        short4v pk;
        #pragma unroll
        for (int t = 0; t < 4; t++)
          pk[t] = (short)(__float_as_uint(p[kg][rq * 4 + t]) >> 16);
        *(short4v*)&psw[lq * 72 + kg * 32 + 8 * rq + 4 * hi] = pk;
      }

    __builtin_amdgcn_s_setprio(1);
    #pragma unroll
    for (int ks = 0; ks < 4; ks++){
      bf16x8 pa = *(const bf16x8*)&psw[lq * 72 + ks * 16 + hi * 8];
      #pragma unroll
      for (int dgrp = 0; dgrp < 2; dgrp++){
        int row = dgrp * 32 + lq;
        int byte = row * 128 + ks * 32 + hi * 16;
        byte ^= (row & 7) << 4;
        bf16x8 vf = *(const bf16x8*)(vls + byte);
        oacc[dgrp] = __builtin_amdgcn_mfma_f32_32x32x16_bf16(pa, vf, oacc[dgrp], 0, 0, 0);
      }
    }
    __builtin_amdgcn_s_setprio(0);

    #pragma unroll
    for (int g = 0; g < 8; g++){ bvA[g] = bvB[g]; mkA[g] = mkB[g]; }
  }

  if (lane < 32){
    int ridx = (b * NHEAD + h) * SSEQ + qw + lq;
    mp[sp * NROWS + ridx] = mrow;
    lp[sp * NROWS + ridx] = lsum;
  }
  #pragma unroll
  for (int r = 0; r < 16; r++){
    int qloc = (r & 3) + 8 * (r >> 2) + 4 * hi;
    int ridx = (b * NHEAD + h) * SSEQ + qw + qloc;
    size_t o = ((size_t)(sp * NROWS + ridx)) * HD;
    Opart[o + lq]      = f2bf(oacc[0][r]);
    Opart[o + 32 + lq] = f2bf(oacc[1][r]);
  }
}

// ---------------- split-KV merge ----------------
__global__ __launch_bounds__(256) void attn_merge(const u16* __restrict__ Opart, const float* __restrict__ mp,
                                                  const float* __restrict__ lp, u16* __restrict__ attn){
  int row = blockIdx.x * 16 + (threadIdx.x >> 4);
  int tx = threadIdx.x & 15;
  float ms[NSPLIT], ls[NSPLIT];
  float m = NEGF;
  #pragma unroll
  for (int sp = 0; sp < NSPLIT; sp++){
    ms[sp] = mp[sp * NROWS + row];
    ls[sp] = lp[sp * NROWS + row];
    if (ls[sp] > 0.f) m = fmaxf(m, ms[sp]);
  }
  float acc0 = 0.f, acc1 = 0.f, acc2 = 0.f, acc3 = 0.f, ltot = 0.f;
  #pragma unroll
  for (int sp = 0; sp < NSPLIT; sp++){
    float e = (ls[sp] > 0.f) ? __expf(ms[sp] - m) : 0.f;
    ltot += ls[sp] * e;
    ushort4 o4 = *(const ushort4*)&Opart[((size_t)(sp * NROWS + row)) * HD + tx*4];
    acc0 += e * bf2f(o4.x);
    acc1 += e * bf2f(o4.y);
    acc2 += e * bf2f(o4.z);
    acc3 += e * bf2f(o4.w);
  }
  float inv = ltot > 0.f ? 1.f / ltot : 0.f;
  int b = row >> 15, h = (row >> 11) & 15, q = row & 2047;
  ushort4 r4;
  r4.x = f2bf(acc0 * inv);
  r4.y = f2bf(acc1 * inv);
  r4.z = f2bf(acc2 * inv);
  r4.w = f2bf(acc3 * inv);
  *(ushort4*)&attn[((size_t)(b * SSEQ + q)) * DIMD + h * HD + tx*4] = r4;
}

// ---------------- launch ----------------
extern "C" void kernel_launch(void* const* d_in, const int* in_sizes, int n_in,
                              void* d_out, int out_size, void* d_ws, size_t ws_size,
                              hipStream_t stream){
  const float* x    = (const float*)d_in[0];
  const unsigned char* mask = (const unsigned char*)d_in[1];
  const float* bias = (const float*)d_in[2];
  const float* Wq   = (const float*)d_in[3];
  const float* Wk   = (const float*)d_in[4];
  const float* Wv   = (const float*)d_in[5];
  const float* Wo   = (const float*)d_in[6];
  const float* W1   = (const float*)d_in[7];
  const float* b1   = (const float*)d_in[8];
  const float* W2   = (const float*)d_in[9];
  const float* b2   = (const float*)d_in[10];
  const float* g1   = (const float*)d_in[11];
  const float* g2   = (const float*)d_in[12];
  float* out = (float*)d_out;

  char* ws = (char*)d_ws;
  size_t off = 0;
  auto take = [&](size_t bytes) -> char* {
    char* p = ws + off;
    off = (off + bytes + 255) & ~(size_t)255;
    return p;
  };
  u16*  wqkv_t = (u16*) take((size_t)3072*1024*2);
  u16*  wo_t   = (u16*) take((size_t)1024*1024*2);
  u16*  w1_t   = (u16*) take((size_t)4096*1024*2);
  u16*  w2_t   = (u16*) take((size_t)1024*4096*2);
  u16*  hbuf   = (u16*) take((size_t)4096*1024*2);
  u16*  qkv    = (u16*) take((size_t)4096*3072*2);
  u16*  attn   = (u16*) take((size_t)4096*1024*2);
  float* x2    = (float*)take((size_t)4096*1024*4);
  u16*  h2     = (u16*) take((size_t)4096*1024*2);
  u16*  fbuf   = (u16*) take((size_t)4096*4096*2);
  unsigned char* nmask = (unsigned char*)take(BB*SSEQ);
  float* mpbuf = (float*)take((size_t)NSPLIT*NROWS*4);
  float* lpbuf = (float*)take((size_t)NSPLIT*NROWS*4);
  u16*  fp2    = (u16*) take((size_t)4*4096*1024*2);   // split-K partials (O-proj, then FFN2)
  u16* Opart = fbuf;   // alias: consumed by attn_merge before FFN1 writes fbuf
  u16* vt_g  = hbuf;   // alias: hbuf dead after QKV GEMM

  hipFuncSetAttribute(reinterpret_cast<const void*>(gemm8p<0>),
                      hipFuncAttributeMaxDynamicSharedMemorySize, 98304);
  hipFuncSetAttribute(reinterpret_cast<const void*>(gemm8p<2>),
                      hipFuncAttributeMaxDynamicSharedMemorySize, 98304);
  hipFuncSetAttribute(reinterpret_cast<const void*>(gemm8p_sk),
                      hipFuncAttributeMaxDynamicSharedMemorySize, 98304);

  normalize_mask<<<1, 1024, 0, stream>>>(mask, nmask);

  dim3 tb(32, 8);
  transpose4_to_bf16<<<dim3(32, 32, 4), tb, 0, stream>>>(Wq, Wk, Wv, Wo, wqkv_t, wo_t);
  transpose_to_bf16<<<dim3(128, 32), tb, 0, stream>>>(W1, w1_t, 1024, 4096);
  transpose_to_bf16<<<dim3(32, 128), tb, 0, stream>>>(W2, w2_t, 4096, 1024);

  rmsnorm_k<<<4096, 256, 0, stream>>>(x, g1, hbuf, DIMD);

  gemm8p<0><<<dim3(3072/256, 4096/256), 512, 98304, stream>>>(hbuf, wqkv_t, qkv, nullptr, 4096, 3072, 1024);

  vtrans<<<dim3(SSEQ/32, 2, BB*NHEAD), tb, 0, stream>>>(qkv, vt_g);

  attn_part<<<dim3(2*SSEQ/128, NHEAD, NSPLIT), 256, 0, stream>>>(qkv, vt_g, bias, nmask, Opart, mpbuf, lpbuf);
  attn_merge<<<dim3(NROWS/16), 256, 0, stream>>>(Opart, mpbuf, lpbuf, attn);

  // O-proj: split-K 256^2 GEMM -> partials; merge + residual + fused RMSNorm2
  gemm8p_sk<<<dim3(1024/256, 4096/256, 4), 512, 98304, stream>>>(attn, wo_t, fp2, 4096, 1024, 1024, 256);
  skmerge_rms<<<dim3(4096*1024/2048), 256, 0, stream>>>(fp2, x, g2, x2, h2);

  gemm8p<2><<<dim3(4096/256, 4096/256), 512, 98304, stream>>>(h2, w1_t, fbuf, b1, 4096, 4096, 1024);

  gemm8p_sk<<<dim3(1024/256, 4096/256, 4), 512, 98304, stream>>>(fbuf, w2_t, fp2, 4096, 1024, 4096, 1024);
  ffn2_merge<<<dim3(4096*1024/2048), 256, 0, stream>>>(fp2, x2, b2, out);
}

// Round 16
// 332.923 us; speedup vs baseline: 1.0325x; 1.0325x over previous
//
#include <hip/hip_runtime.h>
#include <math.h>

typedef __attribute__((ext_vector_type(8))) short   short8;
typedef __attribute__((ext_vector_type(4))) short   short4v;
typedef __attribute__((ext_vector_type(8))) __bf16  bf16x8;
typedef __attribute__((ext_vector_type(4))) float   f32x4;
typedef __attribute__((ext_vector_type(16))) float  f32x16;
typedef unsigned short u16;

#define DIMD 1024
#define NHEAD 16
#define HD 64
#define FFD 4096
#define BB 2
#define SSEQ 2048
#define NSPLIT 2
#define KVSPAN (SSEQ / NSPLIT)
#define NROWS (BB * NHEAD * SSEQ)
#define NEGF -3.4028235e38f

__device__ __forceinline__ u16 f2bf(float f){
  unsigned u = __float_as_uint(f);
  u += 0x7FFFu + ((u >> 16) & 1u);
  return (u16)(u >> 16);
}
__device__ __forceinline__ float bf2f(u16 v){
  return __uint_as_float(((unsigned)v) << 16);
}
__device__ __forceinline__ void gload16(const u16* g, u16* l){
  __builtin_amdgcn_global_load_lds((const __attribute__((address_space(1))) void*)g,
                                   (__attribute__((address_space(3))) void*)l, 16, 0, 0);
}

// ---------------- mask dtype discriminator + normalizer (u8 0/1) ----------------
__global__ void normalize_mask(const unsigned char* __restrict__ m, unsigned char* __restrict__ outm){
  __shared__ int any;
  if (threadIdx.x == 0) any = 0;
  __syncthreads();
  int bad = 0;
  for (int i = threadIdx.x; i < BB * SSEQ; i += 1024)
    if ((i & 3) && m[i]) bad = 1;
  if (bad) atomicOr(&any, 1);
  __syncthreads();
  bool is_i32 = (any == 0);
  if (is_i32){
    const int* mi = (const int*)m;
    for (int k = threadIdx.x; k < BB * SSEQ; k += 1024)
      outm[k] = (unsigned char)(mi[k] != 0);
  } else {
    for (int k = threadIdx.x; k < BB * SSEQ; k += 1024)
      outm[k] = m[k] ? 1 : 0;
  }
}

// ---------------- weight transpose + fp32->bf16 ----------------
__global__ void transpose_to_bf16(const float* __restrict__ W, u16* __restrict__ Wt, int K, int N){
  __shared__ float tile[32][33];
  int n0 = blockIdx.x * 32, k0 = blockIdx.y * 32;
  int tx = threadIdx.x, ty = threadIdx.y;   // 32 x 8
  #pragma unroll
  for (int i = 0; i < 32; i += 8)
    tile[ty + i][tx] = W[(size_t)(k0 + ty + i) * N + n0 + tx];
  __syncthreads();
  #pragma unroll
  for (int i = 0; i < 32; i += 8)
    Wt[(size_t)(n0 + ty + i) * K + k0 + tx] = f2bf(tile[tx][ty + i]);
}

// fused 4x square (1024x1024) transpose: z selects matrix
__global__ void transpose4_to_bf16(const float* __restrict__ Wq, const float* __restrict__ Wk,
                                   const float* __restrict__ Wv, const float* __restrict__ Wo,
                                   u16* __restrict__ Tqkv, u16* __restrict__ To){
  __shared__ float tile[32][33];
  const float* W;
  u16* T;
  switch (blockIdx.z){
    case 0: W = Wq; T = Tqkv;                        break;
    case 1: W = Wk; T = Tqkv + (size_t)1024*1024;    break;
    case 2: W = Wv; T = Tqkv + (size_t)2048*1024;    break;
    default: W = Wo; T = To;                         break;
  }
  int n0 = blockIdx.x * 32, k0 = blockIdx.y * 32;
  int tx = threadIdx.x, ty = threadIdx.y;
  #pragma unroll
  for (int i = 0; i < 32; i += 8)
    tile[ty + i][tx] = W[(size_t)(k0 + ty + i) * 1024 + n0 + tx];
  __syncthreads();
  #pragma unroll
  for (int i = 0; i < 32; i += 8)
    T[(size_t)(n0 + ty + i) * 1024 + k0 + tx] = f2bf(tile[tx][ty + i]);
}

// ---------------- V global transpose: qkv V-block -> vt[b,h][dcol][S] ----------------
__global__ void vtrans(const u16* __restrict__ qkv, u16* __restrict__ vt){
  __shared__ u16 tile[32][33];
  int s0 = blockIdx.x * 32, d0 = blockIdx.y * 32;
  int bh = blockIdx.z;              // b*NHEAD + h
  int b = bh >> 4, h = bh & 15;
  int tx = threadIdx.x, ty = threadIdx.y;
  const u16* src = qkv + (size_t)(b * SSEQ) * 3072 + 2048 + h * HD + d0;
  #pragma unroll
  for (int i = 0; i < 32; i += 8)
    tile[ty + i][tx] = src[(size_t)(s0 + ty + i) * 3072 + tx];
  __syncthreads();
  u16* dst = vt + ((size_t)bh * HD + d0) * SSEQ + s0;
  #pragma unroll
  for (int i = 0; i < 32; i += 8)
    dst[(size_t)(ty + i) * SSEQ + tx] = tile[tx][ty + i];
}

// ---------------- RMSNorm: fp32 in -> bf16 out ----------------
__global__ __launch_bounds__(256) void rmsnorm_k(const float* __restrict__ x, const float* __restrict__ g,
                                                 u16* __restrict__ out, int D){
  int row = blockIdx.x;
  const float* xr = x + (size_t)row * D;
  float ss = 0.f;
  for (int i = threadIdx.x * 4; i < D; i += 1024){
    float4 v = *(const float4*)&xr[i];
    ss += v.x*v.x + v.y*v.y + v.z*v.z + v.w*v.w;
  }
  #pragma unroll
  for (int o = 32; o > 0; o >>= 1) ss += __shfl_down(ss, o);
  __shared__ float red[4];
  if ((threadIdx.x & 63) == 0) red[threadIdx.x >> 6] = ss;
  __syncthreads();
  float tot = red[0] + red[1] + red[2] + red[3];
  float rs = rsqrtf(tot / (float)D + 1e-6f);
  for (int i = threadIdx.x * 4; i < D; i += 1024){
    float4 v  = *(const float4*)&xr[i];
    float4 gv = *(const float4*)&g[i];
    ushort4 o4;
    o4.x = f2bf(v.x * rs * gv.x);
    o4.y = f2bf(v.y * rs * gv.y);
    o4.z = f2bf(v.z * rs * gv.z);
    o4.w = f2bf(v.w * rs * gv.w);
    *(ushort4*)&out[(size_t)row * D + i] = o4;
  }
}

// ---- bijective XCD swizzle for grids with (gridX*gridY) % 8 == 0 ----
__device__ __forceinline__ void xcd_swz(int& bx, int& by){
  int gx = gridDim.x, nwg = gx * gridDim.y;
  int flat = by * gx + bx;
  int q = nwg >> 3;
  flat = (flat & 7) * q + (flat >> 3);
  bx = flat % gx;
  by = flat / gx;
}

// ================= 8-phase-style 256x256 GEMM, BK=32, 3-deep pipeline =================
template<int EPI>
__global__ __launch_bounds__(512, 2) void gemm8p(const u16* __restrict__ A, const u16* __restrict__ Bt,
                                                 u16* __restrict__ outb, const float* __restrict__ bias,
                                                 int M, int N, int K){
  extern __shared__ u16 lds[];   // 3 * 16384 u16
  const int tid = threadIdx.x;
  const int lane = tid & 63, lr = lane >> 4, lc = lane & 15;
  const int wid = tid >> 6, wr = wid >> 2, wc = wid & 3;
  int bx = blockIdx.x, by = blockIdx.y;
  xcd_swz(bx, by);
  const int m0 = by * 256, n0 = bx * 256;
  const int NT = K >> 5;
  const int slot8 = ((lr ^ (lc & 3)) << 3);

  f32x4 acc[8][4];
  #pragma unroll
  for (int i = 0; i < 8; i++)
    #pragma unroll
    for (int j = 0; j < 4; j++) acc[i][j] = (f32x4){0.f,0.f,0.f,0.f};

  const int srow = tid >> 2;
  const int scg  = (tid & 3) ^ (srow & 3);

  auto stage = [&](int t, int buf, int rsel){
    int row = ((rsel & 1) << 7) + srow;
    const u16* src = ((rsel < 2) ? A + (size_t)(m0 + row) * K
                                 : Bt + (size_t)(n0 + row) * K) + t * 32 + scg * 8;
    u16* dst = lds + buf * 16384 + ((rsel & 2) << 12) + ((rsel & 1) << 12) + tid * 8;
    gload16(src, dst);
  };
  auto ldA = [&](int buf, int mi) -> bf16x8 {
    int ra = wr * 128 + mi * 16 + lc;
    return *(const bf16x8*)&lds[buf * 16384 + ra * 32 + slot8];
  };
  auto ldB = [&](int buf, int ni) -> bf16x8 {
    int rb = wc * 64 + ni * 16 + lc;
    return *(const bf16x8*)&lds[buf * 16384 + 8192 + rb * 32 + slot8];
  };

  #pragma unroll
  for (int rs = 0; rs < 4; rs++) stage(0, 0, rs);
  #pragma unroll
  for (int rs = 0; rs < 4; rs++) stage(1, 1, rs);
  asm volatile("s_waitcnt vmcnt(4)" ::: "memory");
  __builtin_amdgcn_s_barrier();

  int buf = 0;
  for (int t = 0; t < NT; t++){
    int sbuf = buf + 2; if (sbuf >= 3) sbuf -= 3;
    bool ds = (t + 2 < NT);
    bf16x8 a[4], b[4];
    #pragma unroll
    for (int mi = 0; mi < 4; mi++) a[mi] = ldA(buf, mi);
    #pragma unroll
    for (int ni = 0; ni < 4; ni++) b[ni] = ldB(buf, ni);
    if (ds){ stage(t + 2, sbuf, 0); stage(t + 2, sbuf, 1); }
    __builtin_amdgcn_s_barrier();
    __builtin_amdgcn_s_setprio(1);
    #pragma unroll
    for (int mi = 0; mi < 4; mi++)
      #pragma unroll
      for (int ni = 0; ni < 4; ni++)
        acc[mi][ni] = __builtin_amdgcn_mfma_f32_16x16x32_bf16(a[mi], b[ni], acc[mi][ni], 0, 0, 0);
    __builtin_amdgcn_s_setprio(0);
    __builtin_amdgcn_s_barrier();
    #pragma unroll
    for (int mi = 0; mi < 4; mi++) a[mi] = ldA(buf, mi + 4);
    if (ds){ stage(t + 2, sbuf, 2); stage(t + 2, sbuf, 3); }
    __builtin_amdgcn_s_barrier();
    __builtin_amdgcn_s_setprio(1);
    #pragma unroll
    for (int mi = 0; mi < 4; mi++)
      #pragma unroll
      for (int ni = 0; ni < 4; ni++)
        acc[mi + 4][ni] = __builtin_amdgcn_mfma_f32_16x16x32_bf16(a[mi], b[ni], acc[mi + 4][ni], 0, 0, 0);
    __builtin_amdgcn_s_setprio(0);
    if (t + 2 < NT)      { asm volatile("s_waitcnt vmcnt(4)" ::: "memory"); }
    else if (t + 1 < NT) { asm volatile("s_waitcnt vmcnt(0)" ::: "memory"); }
    __builtin_amdgcn_s_barrier();
    buf++; if (buf == 3) buf = 0;
  }

  #pragma unroll
  for (int mi = 0; mi < 8; mi++){
    #pragma unroll
    for (int ni = 0; ni < 4; ni++){
      int col = n0 + wc * 64 + ni * 16 + lc;
      #pragma unroll
      for (int r = 0; r < 4; r++){
        int row = m0 + wr * 128 + mi * 16 + lr * 4 + r;
        float v = acc[mi][ni][r];
        if (EPI == 2){
          v += bias[col];
          v = 0.5f * v * (1.f + erff(v * 0.70710678118654752f));
        }
        outb[(size_t)row * N + col] = f2bf(v);
      }
    }
  }
}

// ======== split-K variant: grid.z = K-chunk; writes bf16 partial [sk][M][N] ========
__global__ __launch_bounds__(512, 2) void gemm8p_sk(const u16* __restrict__ A, const u16* __restrict__ Bt,
                                                    u16* __restrict__ part,
                                                    int M, int N, int Kstride, int Klen){
  extern __shared__ u16 lds[];
  const int tid = threadIdx.x;
  const int lane = tid & 63, lr = lane >> 4, lc = lane & 15;
  const int wid = tid >> 6, wr = wid >> 2, wc = wid & 3;
  int bx = blockIdx.x, by = blockIdx.y;
  xcd_swz(bx, by);
  const int sk = blockIdx.z;
  const size_t koff = (size_t)sk * Klen;
  const int m0 = by * 256, n0 = bx * 256;
  const int NT = Klen >> 5;
  const int slot8 = ((lr ^ (lc & 3)) << 3);

  f32x4 acc[8][4];
  #pragma unroll
  for (int i = 0; i < 8; i++)
    #pragma unroll
    for (int j = 0; j < 4; j++) acc[i][j] = (f32x4){0.f,0.f,0.f,0.f};

  const int srow = tid >> 2;
  const int scg  = (tid & 3) ^ (srow & 3);

  auto stage = [&](int t, int buf, int rsel){
    int row = ((rsel & 1) << 7) + srow;
    const u16* src = ((rsel < 2) ? A + (size_t)(m0 + row) * Kstride
                                 : Bt + (size_t)(n0 + row) * Kstride) + koff + t * 32 + scg * 8;
    u16* dst = lds + buf * 16384 + ((rsel & 2) << 12) + ((rsel & 1) << 12) + tid * 8;
    gload16(src, dst);
  };
  auto ldA = [&](int buf, int mi) -> bf16x8 {
    int ra = wr * 128 + mi * 16 + lc;
    return *(const bf16x8*)&lds[buf * 16384 + ra * 32 + slot8];
  };
  auto ldB = [&](int buf, int ni) -> bf16x8 {
    int rb = wc * 64 + ni * 16 + lc;
    return *(const bf16x8*)&lds[buf * 16384 + 8192 + rb * 32 + slot8];
  };

  #pragma unroll
  for (int rs = 0; rs < 4; rs++) stage(0, 0, rs);
  #pragma unroll
  for (int rs = 0; rs < 4; rs++) stage(1, 1, rs);
  asm volatile("s_waitcnt vmcnt(4)" ::: "memory");
  __builtin_amdgcn_s_barrier();

  int buf = 0;
  for (int t = 0; t < NT; t++){
    int sbuf = buf + 2; if (sbuf >= 3) sbuf -= 3;
    bool ds = (t + 2 < NT);
    bf16x8 a[4], b[4];
    #pragma unroll
    for (int mi = 0; mi < 4; mi++) a[mi] = ldA(buf, mi);
    #pragma unroll
    for (int ni = 0; ni < 4; ni++) b[ni] = ldB(buf, ni);
    if (ds){ stage(t + 2, sbuf, 0); stage(t + 2, sbuf, 1); }
    __builtin_amdgcn_s_barrier();
    __builtin_amdgcn_s_setprio(1);
    #pragma unroll
    for (int mi = 0; mi < 4; mi++)
      #pragma unroll
      for (int ni = 0; ni < 4; ni++)
        acc[mi][ni] = __builtin_amdgcn_mfma_f32_16x16x32_bf16(a[mi], b[ni], acc[mi][ni], 0, 0, 0);
    __builtin_amdgcn_s_setprio(0);
    __builtin_amdgcn_s_barrier();
    #pragma unroll
    for (int mi = 0; mi < 4; mi++) a[mi] = ldA(buf, mi + 4);
    if (ds){ stage(t + 2, sbuf, 2); stage(t + 2, sbuf, 3); }
    __builtin_amdgcn_s_barrier();
    __builtin_amdgcn_s_setprio(1);
    #pragma unroll
    for (int mi = 0; mi < 4; mi++)
      #pragma unroll
      for (int ni = 0; ni < 4; ni++)
        acc[mi + 4][ni] = __builtin_amdgcn_mfma_f32_16x16x32_bf16(a[mi], b[ni], acc[mi + 4][ni], 0, 0, 0);
    __builtin_amdgcn_s_setprio(0);
    if (t + 2 < NT)      { asm volatile("s_waitcnt vmcnt(4)" ::: "memory"); }
    else if (t + 1 < NT) { asm volatile("s_waitcnt vmcnt(0)" ::: "memory"); }
    __builtin_amdgcn_s_barrier();
    buf++; if (buf == 3) buf = 0;
  }

  u16* po = part + (size_t)sk * M * N;
  #pragma unroll
  for (int mi = 0; mi < 8; mi++){
    #pragma unroll
    for (int ni = 0; ni < 4; ni++){
      int col = n0 + wc * 64 + ni * 16 + lc;
      #pragma unroll
      for (int r = 0; r < 4; r++){
        int row = m0 + wr * 128 + mi * 16 + lr * 4 + r;
        po[(size_t)row * N + col] = f2bf(acc[mi][ni][r]);
      }
    }
  }
}

// ---- O-proj merge + residual + fused RMSNorm2: writes x2 (fp32) AND h2 (bf16) ----
// block = 256 threads * 8 elems = 2048 = 2 rows of 1024. waves 0,1 -> row0; 2,3 -> row1.
__global__ __launch_bounds__(256) void skmerge_rms(const u16* __restrict__ part, const float* __restrict__ resid,
                                                   const float* __restrict__ g2, float* __restrict__ x2,
                                                   u16* __restrict__ h2){
  size_t i = ((size_t)blockIdx.x * 256 + threadIdx.x) * 8;
  int col = (int)(i & (DIMD - 1));
  const size_t MN = (size_t)4096 * DIMD;
  short8 a0 = *(const short8*)&part[i];
  short8 a1 = *(const short8*)&part[MN + i];
  short8 a2 = *(const short8*)&part[2 * MN + i];
  short8 a3 = *(const short8*)&part[3 * MN + i];
  float4 xa = *(const float4*)&resid[i];
  float4 xb = *(const float4*)&resid[i + 4];
  float o[8];
  #pragma unroll
  for (int j = 0; j < 8; j++)
    o[j] = (bf2f((u16)a0[j]) + bf2f((u16)a1[j])) + (bf2f((u16)a2[j]) + bf2f((u16)a3[j]));
  o[0] += xa.x; o[1] += xa.y; o[2] += xa.z; o[3] += xa.w;
  o[4] += xb.x; o[5] += xb.y; o[6] += xb.z; o[7] += xb.w;
  *(float4*)&x2[i]     = (float4){o[0], o[1], o[2], o[3]};
  *(float4*)&x2[i + 4] = (float4){o[4], o[5], o[6], o[7]};

  // fused RMSNorm over each 1024-row
  float ss = 0.f;
  #pragma unroll
  for (int j = 0; j < 8; j++) ss += o[j] * o[j];
  #pragma unroll
  for (int off = 32; off > 0; off >>= 1) ss += __shfl_down(ss, off);
  __shared__ float red[4];
  if ((threadIdx.x & 63) == 0) red[threadIdx.x >> 6] = ss;
  __syncthreads();
  float tot = (threadIdx.x < 128) ? (red[0] + red[1]) : (red[2] + red[3]);
  float rs = rsqrtf(tot / (float)DIMD + 1e-6f);
  float4 ga = *(const float4*)&g2[col];
  float4 gb = *(const float4*)&g2[col + 4];
  ushort4 h0, h1;
  h0.x = f2bf(o[0] * rs * ga.x); h0.y = f2bf(o[1] * rs * ga.y);
  h0.z = f2bf(o[2] * rs * ga.z); h0.w = f2bf(o[3] * rs * ga.w);
  h1.x = f2bf(o[4] * rs * gb.x); h1.y = f2bf(o[5] * rs * gb.y);
  h1.z = f2bf(o[6] * rs * gb.z); h1.w = f2bf(o[7] * rs * gb.w);
  *(ushort4*)&h2[i]     = h0;
  *(ushort4*)&h2[i + 4] = h1;
}

// merge 4 bf16 partials + resid + bias -> fp32 out  (FFN2)
__global__ __launch_bounds__(256) void ffn2_merge(const u16* __restrict__ part, const float* __restrict__ x2,
                                                  const float* __restrict__ b2, float* __restrict__ out){
  size_t i = ((size_t)blockIdx.x * 256 + threadIdx.x) * 8;
  int col = (int)(i & (DIMD - 1));
  const size_t MN = (size_t)4096 * DIMD;
  short8 a0 = *(const short8*)&part[i];
  short8 a1 = *(const short8*)&part[MN + i];
  short8 a2 = *(const short8*)&part[2 * MN + i];
  short8 a3 = *(const short8*)&part[3 * MN + i];
  float r[8];
  #pragma unroll
  for (int j = 0; j < 8; j++)
    r[j] = (bf2f((u16)a0[j]) + bf2f((u16)a1[j])) + (bf2f((u16)a2[j]) + bf2f((u16)a3[j]));
  float4 xa = *(const float4*)&x2[i];
  float4 xb = *(const float4*)&x2[i + 4];
  float4 ba = *(const float4*)&b2[col];
  float4 bb = *(const float4*)&b2[col + 4];
  float4 o0 = {r[0] + xa.x + ba.x, r[1] + xa.y + ba.y, r[2] + xa.z + ba.z, r[3] + xa.w + ba.w};
  float4 o1 = {r[4] + xb.x + bb.x, r[5] + xb.y + bb.y, r[6] + xb.z + bb.z, r[7] + xb.w + bb.w};
  *(float4*)&out[i] = o0;
  *(float4*)&out[i + 4] = o1;
}

// ---------------- flash attention: 32x32 swapped QK^T (proven 333us config) ----------------
__global__ __launch_bounds__(256) void attn_part(const u16* __restrict__ qkv, const u16* __restrict__ vt,
                                                 const float* __restrict__ bias,
                                                 const unsigned char* __restrict__ mask,
                                                 u16* __restrict__ Opart, float* __restrict__ mp, float* __restrict__ lp){
  __shared__ u16 Ks [64 * 64];   // [key][d]   XOR-swizzled
  __shared__ u16 Vts[64 * 64];   // [d][key]   XOR-swizzled
  __shared__ u16 Ps [4 * 32 * 72]; // per-wave [q=32][key=64 (+pad)]

  const int tid = threadIdx.x;
  const int lane = tid & 63, hi = lane >> 5, lq = lane & 31;
  const int wq = tid >> 6;
  const int b  = blockIdx.x & 1;
  const int qb = blockIdx.x >> 1;
  const int h  = blockIdx.y;
  const int sp = blockIdx.z;
  const int qw = qb * 128 + wq * 32;
  const int kv_lo = sp * KVSPAN, kv_hi = kv_lo + KVSPAN;

  char* kls = (char*)Ks;
  char* vls = (char*)Vts;
  u16*  psw = Ps + wq * 32 * 72;

  bf16x8 qf[4];
  {
    const u16* qp = qkv + ((size_t)(b * SSEQ + qw + lq)) * 3072 + h * HD + hi * 8;
    #pragma unroll
    for (int dstep = 0; dstep < 4; dstep++) qf[dstep] = *(const bf16x8*)(qp + dstep * 16);
  }

  const u16* kbase = qkv + (size_t)b * SSEQ * 3072 + 1024 + h * HD;
  const u16* vbase = vt + (size_t)(b * NHEAD + h) * HD * SSEQ;
  const int c0 = tid, c1 = tid + 256;
  auto kaddr = [&](int kv0, int c){ return kbase + (size_t)(kv0 + (c >> 3)) * 3072 + (c & 7) * 8; };
  auto vaddr = [&](int kv0, int c){ return vbase + (size_t)(c >> 3) * SSEQ + kv0 + (c & 7) * 8; };
  auto sstore = [&](char* base, int c, short8 v){
    int byte = (c >> 3) * 128 + (c & 7) * 16;
    byte ^= ((c >> 3) & 7) << 4;
    *(short8*)(base + byte) = v;
  };

  const float* brow = bias + ((size_t)h * SSEQ + (qw + lq)) * SSEQ;
  const unsigned char* mbase = mask + b * SSEQ;

  short8 kr0 = *(const short8*)kaddr(kv_lo, c0);
  short8 kr1 = *(const short8*)kaddr(kv_lo, c1);
  short8 vr0 = *(const short8*)vaddr(kv_lo, c0);
  short8 vr1 = *(const short8*)vaddr(kv_lo, c1);

  float mrow = NEGF, lsum = 0.f;
  f32x16 oacc[2];
  #pragma unroll
  for (int g = 0; g < 2; g++)
    #pragma unroll
    for (int r = 0; r < 16; r++) oacc[g][r] = 0.f;

  for (int kv0 = kv_lo; kv0 < kv_hi; kv0 += 64){
    float4 bv[8]; unsigned mk[8];
    #pragma unroll
    for (int kg = 0; kg < 2; kg++)
      #pragma unroll
      for (int rq = 0; rq < 4; rq++){
        int base = kv0 + kg * 32 + 8 * rq + 4 * hi;
        bv[kg*4+rq] = *(const float4*)&brow[base];
        mk[kg*4+rq] = *(const unsigned*)&mbase[base];
      }

    __syncthreads();
    sstore(kls, c0, kr0); sstore(kls, c1, kr1);
    sstore(vls, c0, vr0); sstore(vls, c1, vr1);
    __syncthreads();

    {
      int nxt = (kv0 + 64 < kv_hi) ? kv0 + 64 : kv_lo;
      kr0 = *(const short8*)kaddr(nxt, c0);
      kr1 = *(const short8*)kaddr(nxt, c1);
      vr0 = *(const short8*)vaddr(nxt, c0);
      vr1 = *(const short8*)vaddr(nxt, c1);
    }

    f32x16 acc[2];
    #pragma unroll
    for (int g = 0; g < 2; g++)
      #pragma unroll
      for (int r = 0; r < 16; r++) acc[g][r] = 0.f;
    __builtin_amdgcn_s_setprio(1);
    #pragma unroll
    for (int kg = 0; kg < 2; kg++){
      int row = kg * 32 + lq;
      #pragma unroll
      for (int dstep = 0; dstep < 4; dstep++){
        int byte = row * 128 + dstep * 32 + hi * 16;
        byte ^= (row & 7) << 4;
        bf16x8 kf = *(const bf16x8*)(kls + byte);
        acc[kg] = __builtin_amdgcn_mfma_f32_32x32x16_bf16(kf, qf[dstep], acc[kg], 0, 0, 0);
      }
    }
    __builtin_amdgcn_s_setprio(0);

    float p[2][16];
    float tm = NEGF;
    #pragma unroll
    for (int kg = 0; kg < 2; kg++)
      #pragma unroll
      for (int r = 0; r < 16; r++){
        int g = kg * 4 + (r >> 2);
        bool m = ((mk[g] >> (8 * (r & 3))) & 0xffu) != 0;
        float v = acc[kg][r] * 0.125f + ((const float*)&bv[g])[r & 3];
        v = m ? NEGF : v;
        p[kg][r] = v;
        tm = fmaxf(tm, v);
      }
    tm = fmaxf(tm, __shfl_xor(tm, 32));

    if (__any(tm > mrow + 5.f)){
      float mnew = fmaxf(mrow, tm);
      float corr = __expf(mrow - mnew);
      lsum *= corr;
      mrow = mnew;
      #pragma unroll
      for (int r = 0; r < 16; r++){
        float cr = __shfl(corr, (r & 3) + 8 * (r >> 2) + 4 * hi);
        oacc[0][r] *= cr;
        oacc[1][r] *= cr;
      }
    }

    float psum = 0.f;
    #pragma unroll
    for (int kg = 0; kg < 2; kg++)
      #pragma unroll
      for (int r = 0; r < 16; r++){
        float sv = p[kg][r];
        float e = (sv < -1e30f) ? 0.f : __expf(sv - mrow);
        p[kg][r] = e;
        psum += e;
      }
    psum += __shfl_xor(psum, 32);
    lsum += psum;

    #pragma unroll
    for (int kg = 0; kg < 2; kg++)
      #pragma unroll
      for (int rq = 0; rq < 4; rq++){
        short4v pk;
        #pragma unroll
        for (int t = 0; t < 4; t++)
          pk[t] = (short)(__float_as_uint(p[kg][rq * 4 + t]) >> 16);
        *(short4v*)&psw[lq * 72 + kg * 32 + 8 * rq + 4 * hi] = pk;
      }

    __builtin_amdgcn_s_setprio(1);
    #pragma unroll
    for (int ks = 0; ks < 4; ks++){
      bf16x8 pa = *(const bf16x8*)&psw[lq * 72 + ks * 16 + hi * 8];
      #pragma unroll
      for (int dgrp = 0; dgrp < 2; dgrp++){
        int row = dgrp * 32 + lq;
        int byte = row * 128 + ks * 32 + hi * 16;
        byte ^= (row & 7) << 4;
        bf16x8 vf = *(const bf16x8*)(vls + byte);
        oacc[dgrp] = __builtin_amdgcn_mfma_f32_32x32x16_bf16(pa, vf, oacc[dgrp], 0, 0, 0);
      }
    }
    __builtin_amdgcn_s_setprio(0);
  }

  if (lane < 32){
    int ridx = (b * NHEAD + h) * SSEQ + qw + lq;
    mp[sp * NROWS + ridx] = mrow;
    lp[sp * NROWS + ridx] = lsum;
  }
  #pragma unroll
  for (int r = 0; r < 16; r++){
    int qloc = (r & 3) + 8 * (r >> 2) + 4 * hi;
    int ridx = (b * NHEAD + h) * SSEQ + qw + qloc;
    size_t o = ((size_t)(sp * NROWS + ridx)) * HD;
    Opart[o + lq]      = f2bf(oacc[0][r]);
    Opart[o + 32 + lq] = f2bf(oacc[1][r]);
  }
}

// ---------------- split-KV merge ----------------
__global__ __launch_bounds__(256) void attn_merge(const u16* __restrict__ Opart, const float* __restrict__ mp,
                                                  const float* __restrict__ lp, u16* __restrict__ attn){
  int row = blockIdx.x * 16 + (threadIdx.x >> 4);
  int tx = threadIdx.x & 15;
  float ms[NSPLIT], ls[NSPLIT];
  float m = NEGF;
  #pragma unroll
  for (int sp = 0; sp < NSPLIT; sp++){
    ms[sp] = mp[sp * NROWS + row];
    ls[sp] = lp[sp * NROWS + row];
    if (ls[sp] > 0.f) m = fmaxf(m, ms[sp]);
  }
  float acc0 = 0.f, acc1 = 0.f, acc2 = 0.f, acc3 = 0.f, ltot = 0.f;
  #pragma unroll
  for (int sp = 0; sp < NSPLIT; sp++){
    float e = (ls[sp] > 0.f) ? __expf(ms[sp] - m) : 0.f;
    ltot += ls[sp] * e;
    ushort4 o4 = *(const ushort4*)&Opart[((size_t)(sp * NROWS + row)) * HD + tx*4];
    acc0 += e * bf2f(o4.x);
    acc1 += e * bf2f(o4.y);
    acc2 += e * bf2f(o4.z);
    acc3 += e * bf2f(o4.w);
  }
  float inv = ltot > 0.f ? 1.f / ltot : 0.f;
  int b = row >> 15, h = (row >> 11) & 15, q = row & 2047;
  ushort4 r4;
  r4.x = f2bf(acc0 * inv);
  r4.y = f2bf(acc1 * inv);
  r4.z = f2bf(acc2 * inv);
  r4.w = f2bf(acc3 * inv);
  *(ushort4*)&attn[((size_t)(b * SSEQ + q)) * DIMD + h * HD + tx*4] = r4;
}

// ---------------- launch ----------------
extern "C" void kernel_launch(void* const* d_in, const int* in_sizes, int n_in,
                              void* d_out, int out_size, void* d_ws, size_t ws_size,
                              hipStream_t stream){
  const float* x    = (const float*)d_in[0];
  const unsigned char* mask = (const unsigned char*)d_in[1];
  const float* bias = (const float*)d_in[2];
  const float* Wq   = (const float*)d_in[3];
  const float* Wk   = (const float*)d_in[4];
  const float* Wv   = (const float*)d_in[5];
  const float* Wo   = (const float*)d_in[6];
  const float* W1   = (const float*)d_in[7];
  const float* b1   = (const float*)d_in[8];
  const float* W2   = (const float*)d_in[9];
  const float* b2   = (const float*)d_in[10];
  const float* g1   = (const float*)d_in[11];
  const float* g2   = (const float*)d_in[12];
  float* out = (float*)d_out;

  char* ws = (char*)d_ws;
  size_t off = 0;
  auto take = [&](size_t bytes) -> char* {
    char* p = ws + off;
    off = (off + bytes + 255) & ~(size_t)255;
    return p;
  };
  u16*  wqkv_t = (u16*) take((size_t)3072*1024*2);
  u16*  wo_t   = (u16*) take((size_t)1024*1024*2);
  u16*  w1_t   = (u16*) take((size_t)4096*1024*2);
  u16*  w2_t   = (u16*) take((size_t)1024*4096*2);
  u16*  hbuf   = (u16*) take((size_t)4096*1024*2);
  u16*  qkv    = (u16*) take((size_t)4096*3072*2);
  u16*  attn   = (u16*) take((size_t)4096*1024*2);
  float* x2    = (float*)take((size_t)4096*1024*4);
  u16*  h2     = (u16*) take((size_t)4096*1024*2);
  u16*  fbuf   = (u16*) take((size_t)4096*4096*2);
  unsigned char* nmask = (unsigned char*)take(BB*SSEQ);
  float* mpbuf = (float*)take((size_t)NSPLIT*NROWS*4);
  float* lpbuf = (float*)take((size_t)NSPLIT*NROWS*4);
  u16*  fp2    = (u16*) take((size_t)4*4096*1024*2);   // split-K partials (O-proj, then FFN2)
  u16* Opart = fbuf;   // alias: consumed by attn_merge before FFN1 writes fbuf
  u16* vt_g  = hbuf;   // alias: hbuf dead after QKV GEMM

  hipFuncSetAttribute(reinterpret_cast<const void*>(gemm8p<0>),
                      hipFuncAttributeMaxDynamicSharedMemorySize, 98304);
  hipFuncSetAttribute(reinterpret_cast<const void*>(gemm8p<2>),
                      hipFuncAttributeMaxDynamicSharedMemorySize, 98304);
  hipFuncSetAttribute(reinterpret_cast<const void*>(gemm8p_sk),
                      hipFuncAttributeMaxDynamicSharedMemorySize, 98304);

  normalize_mask<<<1, 1024, 0, stream>>>(mask, nmask);

  dim3 tb(32, 8);
  transpose4_to_bf16<<<dim3(32, 32, 4), tb, 0, stream>>>(Wq, Wk, Wv, Wo, wqkv_t, wo_t);
  transpose_to_bf16<<<dim3(128, 32), tb, 0, stream>>>(W1, w1_t, 1024, 4096);
  transpose_to_bf16<<<dim3(32, 128), tb, 0, stream>>>(W2, w2_t, 4096, 1024);

  rmsnorm_k<<<4096, 256, 0, stream>>>(x, g1, hbuf, DIMD);

  gemm8p<0><<<dim3(3072/256, 4096/256), 512, 98304, stream>>>(hbuf, wqkv_t, qkv, nullptr, 4096, 3072, 1024);

  vtrans<<<dim3(SSEQ/32, 2, BB*NHEAD), tb, 0, stream>>>(qkv, vt_g);

  attn_part<<<dim3(2*SSEQ/128, NHEAD, NSPLIT), 256, 0, stream>>>(qkv, vt_g, bias, nmask, Opart, mpbuf, lpbuf);
  attn_merge<<<dim3(NROWS/16), 256, 0, stream>>>(Opart, mpbuf, lpbuf, attn);

  // O-proj: split-K 256^2 GEMM -> partials; merge + residual + fused RMSNorm2
  gemm8p_sk<<<dim3(1024/256, 4096/256, 4), 512, 98304, stream>>>(attn, wo_t, fp2, 4096, 1024, 1024, 256);
  skmerge_rms<<<dim3(4096*1024/2048), 256, 0, stream>>>(fp2, x, g2, x2, h2);

  gemm8p<2><<<dim3(4096/256, 4096/256), 512, 98304, stream>>>(h2, w1_t, fbuf, b1, 4096, 4096, 1024);

  gemm8p_sk<<<dim3(1024/256, 4096/256, 4), 512, 98304, stream>>>(fbuf, w2_t, fp2, 4096, 1024, 4096, 1024);
  ffn2_merge<<<dim3(4096*1024/2048), 256, 0, stream>>>(fp2, x2, b2, out);
}

// Round 17
// 331.592 us; speedup vs baseline: 1.0367x; 1.0040x over previous
//
#include <hip/hip_runtime.h>
#include <math.h>

typedef __attribute__((ext_vector_type(8))) short   short8;
typedef __attribute__((ext_vector_type(4))) short   short4v;
typedef __attribute__((ext_vector_type(8))) __bf16  bf16x8;
typedef __attribute__((ext_vector_type(4))) float   f32x4;
typedef __attribute__((ext_vector_type(16))) float  f32x16;
typedef unsigned short u16;

#define DIMD 1024
#define NHEAD 16
#define HD 64
#define FFD 4096
#define BB 2
#define SSEQ 2048
#define NSPLIT 2
#define KVSPAN (SSEQ / NSPLIT)
#define NROWS (BB * NHEAD * SSEQ)
#define NEGF -3.4028235e38f

__device__ __forceinline__ u16 f2bf(float f){
  unsigned u = __float_as_uint(f);
  u += 0x7FFFu + ((u >> 16) & 1u);
  return (u16)(u >> 16);
}
__device__ __forceinline__ float bf2f(u16 v){
  return __uint_as_float(((unsigned)v) << 16);
}
__device__ __forceinline__ void gload16(const u16* g, u16* l){
  __builtin_amdgcn_global_load_lds((const __attribute__((address_space(1))) void*)g,
                                   (__attribute__((address_space(3))) void*)l, 16, 0, 0);
}

// ---------------- mask dtype discriminator + normalizer (u8 0/1) ----------------
__global__ void normalize_mask(const unsigned char* __restrict__ m, unsigned char* __restrict__ outm){
  __shared__ int any;
  if (threadIdx.x == 0) any = 0;
  __syncthreads();
  int bad = 0;
  for (int i = threadIdx.x; i < BB * SSEQ; i += 1024)
    if ((i & 3) && m[i]) bad = 1;
  if (bad) atomicOr(&any, 1);
  __syncthreads();
  bool is_i32 = (any == 0);
  if (is_i32){
    const int* mi = (const int*)m;
    for (int k = threadIdx.x; k < BB * SSEQ; k += 1024)
      outm[k] = (unsigned char)(mi[k] != 0);
  } else {
    for (int k = threadIdx.x; k < BB * SSEQ; k += 1024)
      outm[k] = m[k] ? 1 : 0;
  }
}

// ---------------- weight transpose + fp32->bf16 ----------------
__global__ void transpose_to_bf16(const float* __restrict__ W, u16* __restrict__ Wt, int K, int N){
  __shared__ float tile[32][33];
  int n0 = blockIdx.x * 32, k0 = blockIdx.y * 32;
  int tx = threadIdx.x, ty = threadIdx.y;   // 32 x 8
  #pragma unroll
  for (int i = 0; i < 32; i += 8)
    tile[ty + i][tx] = W[(size_t)(k0 + ty + i) * N + n0 + tx];
  __syncthreads();
  #pragma unroll
  for (int i = 0; i < 32; i += 8)
    Wt[(size_t)(n0 + ty + i) * K + k0 + tx] = f2bf(tile[tx][ty + i]);
}

// fused 4x square (1024x1024) transpose: z selects matrix
__global__ void transpose4_to_bf16(const float* __restrict__ Wq, const float* __restrict__ Wk,
                                   const float* __restrict__ Wv, const float* __restrict__ Wo,
                                   u16* __restrict__ Tqkv, u16* __restrict__ To){
  __shared__ float tile[32][33];
  const float* W;
  u16* T;
  switch (blockIdx.z){
    case 0: W = Wq; T = Tqkv;                        break;
    case 1: W = Wk; T = Tqkv + (size_t)1024*1024;    break;
    case 2: W = Wv; T = Tqkv + (size_t)2048*1024;    break;
    default: W = Wo; T = To;                         break;
  }
  int n0 = blockIdx.x * 32, k0 = blockIdx.y * 32;
  int tx = threadIdx.x, ty = threadIdx.y;
  #pragma unroll
  for (int i = 0; i < 32; i += 8)
    tile[ty + i][tx] = W[(size_t)(k0 + ty + i) * 1024 + n0 + tx];
  __syncthreads();
  #pragma unroll
  for (int i = 0; i < 32; i += 8)
    T[(size_t)(n0 + ty + i) * 1024 + k0 + tx] = f2bf(tile[tx][ty + i]);
}

// ---------------- V global transpose: qkv V-block -> vt[b,h][dcol][S] ----------------
__global__ void vtrans(const u16* __restrict__ qkv, u16* __restrict__ vt){
  __shared__ u16 tile[32][33];
  int s0 = blockIdx.x * 32, d0 = blockIdx.y * 32;
  int bh = blockIdx.z;              // b*NHEAD + h
  int b = bh >> 4, h = bh & 15;
  int tx = threadIdx.x, ty = threadIdx.y;
  const u16* src = qkv + (size_t)(b * SSEQ) * 3072 + 2048 + h * HD + d0;
  #pragma unroll
  for (int i = 0; i < 32; i += 8)
    tile[ty + i][tx] = src[(size_t)(s0 + ty + i) * 3072 + tx];
  __syncthreads();
  u16* dst = vt + ((size_t)bh * HD + d0) * SSEQ + s0;
  #pragma unroll
  for (int i = 0; i < 32; i += 8)
    dst[(size_t)(ty + i) * SSEQ + tx] = tile[tx][ty + i];
}

// ---------------- RMSNorm: fp32 in -> bf16 out ----------------
__global__ __launch_bounds__(256) void rmsnorm_k(const float* __restrict__ x, const float* __restrict__ g,
                                                 u16* __restrict__ out, int D){
  int row = blockIdx.x;
  const float* xr = x + (size_t)row * D;
  float ss = 0.f;
  for (int i = threadIdx.x * 4; i < D; i += 1024){
    float4 v = *(const float4*)&xr[i];
    ss += v.x*v.x + v.y*v.y + v.z*v.z + v.w*v.w;
  }
  #pragma unroll
  for (int o = 32; o > 0; o >>= 1) ss += __shfl_down(ss, o);
  __shared__ float red[4];
  if ((threadIdx.x & 63) == 0) red[threadIdx.x >> 6] = ss;
  __syncthreads();
  float tot = red[0] + red[1] + red[2] + red[3];
  float rs = rsqrtf(tot / (float)D + 1e-6f);
  for (int i = threadIdx.x * 4; i < D; i += 1024){
    float4 v  = *(const float4*)&xr[i];
    float4 gv = *(const float4*)&g[i];
    ushort4 o4;
    o4.x = f2bf(v.x * rs * gv.x);
    o4.y = f2bf(v.y * rs * gv.y);
    o4.z = f2bf(v.z * rs * gv.z);
    o4.w = f2bf(v.w * rs * gv.w);
    *(ushort4*)&out[(size_t)row * D + i] = o4;
  }
}

// ---- bijective XCD swizzle for grids with (gridX*gridY) % 8 == 0 ----
__device__ __forceinline__ void xcd_swz(int& bx, int& by){
  int gx = gridDim.x, nwg = gx * gridDim.y;
  int flat = by * gx + bx;
  int q = nwg >> 3;
  flat = (flat & 7) * q + (flat >> 3);
  bx = flat % gx;
  by = flat / gx;
}

// ================= 8-phase-style 256x256 GEMM, BK=32, 3-deep pipeline =================
template<int EPI>
__global__ __launch_bounds__(512, 2) void gemm8p(const u16* __restrict__ A, const u16* __restrict__ Bt,
                                                 u16* __restrict__ outb, const float* __restrict__ bias,
                                                 int M, int N, int K){
  extern __shared__ u16 lds[];   // 3 * 16384 u16
  const int tid = threadIdx.x;
  const int lane = tid & 63, lr = lane >> 4, lc = lane & 15;
  const int wid = tid >> 6, wr = wid >> 2, wc = wid & 3;
  int bx = blockIdx.x, by = blockIdx.y;
  xcd_swz(bx, by);
  const int m0 = by * 256, n0 = bx * 256;
  const int NT = K >> 5;
  const int slot8 = ((lr ^ (lc & 3)) << 3);

  f32x4 acc[8][4];
  #pragma unroll
  for (int i = 0; i < 8; i++)
    #pragma unroll
    for (int j = 0; j < 4; j++) acc[i][j] = (f32x4){0.f,0.f,0.f,0.f};

  const int srow = tid >> 2;
  const int scg  = (tid & 3) ^ (srow & 3);

  auto stage = [&](int t, int buf, int rsel){
    int row = ((rsel & 1) << 7) + srow;
    const u16* src = ((rsel < 2) ? A + (size_t)(m0 + row) * K
                                 : Bt + (size_t)(n0 + row) * K) + t * 32 + scg * 8;
    u16* dst = lds + buf * 16384 + ((rsel & 2) << 12) + ((rsel & 1) << 12) + tid * 8;
    gload16(src, dst);
  };
  auto ldA = [&](int buf, int mi) -> bf16x8 {
    int ra = wr * 128 + mi * 16 + lc;
    return *(const bf16x8*)&lds[buf * 16384 + ra * 32 + slot8];
  };
  auto ldB = [&](int buf, int ni) -> bf16x8 {
    int rb = wc * 64 + ni * 16 + lc;
    return *(const bf16x8*)&lds[buf * 16384 + 8192 + rb * 32 + slot8];
  };

  #pragma unroll
  for (int rs = 0; rs < 4; rs++) stage(0, 0, rs);
  #pragma unroll
  for (int rs = 0; rs < 4; rs++) stage(1, 1, rs);
  asm volatile("s_waitcnt vmcnt(4)" ::: "memory");
  __builtin_amdgcn_s_barrier();

  int buf = 0;
  for (int t = 0; t < NT; t++){
    int sbuf = buf + 2; if (sbuf >= 3) sbuf -= 3;
    bool ds = (t + 2 < NT);
    bf16x8 a[4], b[4];
    #pragma unroll
    for (int mi = 0; mi < 4; mi++) a[mi] = ldA(buf, mi);
    #pragma unroll
    for (int ni = 0; ni < 4; ni++) b[ni] = ldB(buf, ni);
    if (ds){ stage(t + 2, sbuf, 0); stage(t + 2, sbuf, 1); }
    __builtin_amdgcn_s_barrier();
    __builtin_amdgcn_s_setprio(1);
    #pragma unroll
    for (int mi = 0; mi < 4; mi++)
      #pragma unroll
      for (int ni = 0; ni < 4; ni++)
        acc[mi][ni] = __builtin_amdgcn_mfma_f32_16x16x32_bf16(a[mi], b[ni], acc[mi][ni], 0, 0, 0);
    __builtin_amdgcn_s_setprio(0);
    __builtin_amdgcn_s_barrier();
    #pragma unroll
    for (int mi = 0; mi < 4; mi++) a[mi] = ldA(buf, mi + 4);
    if (ds){ stage(t + 2, sbuf, 2); stage(t + 2, sbuf, 3); }
    __builtin_amdgcn_s_barrier();
    __builtin_amdgcn_s_setprio(1);
    #pragma unroll
    for (int mi = 0; mi < 4; mi++)
      #pragma unroll
      for (int ni = 0; ni < 4; ni++)
        acc[mi + 4][ni] = __builtin_amdgcn_mfma_f32_16x16x32_bf16(a[mi], b[ni], acc[mi + 4][ni], 0, 0, 0);
    __builtin_amdgcn_s_setprio(0);
    if (t + 2 < NT)      { asm volatile("s_waitcnt vmcnt(4)" ::: "memory"); }
    else if (t + 1 < NT) { asm volatile("s_waitcnt vmcnt(0)" ::: "memory"); }
    __builtin_amdgcn_s_barrier();
    buf++; if (buf == 3) buf = 0;
  }

  #pragma unroll
  for (int mi = 0; mi < 8; mi++){
    #pragma unroll
    for (int ni = 0; ni < 4; ni++){
      int col = n0 + wc * 64 + ni * 16 + lc;
      #pragma unroll
      for (int r = 0; r < 4; r++){
        int row = m0 + wr * 128 + mi * 16 + lr * 4 + r;
        float v = acc[mi][ni][r];
        if (EPI == 2){
          v += bias[col];
          v = 0.5f * v * (1.f + erff(v * 0.70710678118654752f));
        }
        outb[(size_t)row * N + col] = f2bf(v);
      }
    }
  }
}

// ======== split-K variant: grid.z = K-chunk; writes bf16 partial [sk][M][N] ========
__global__ __launch_bounds__(512, 2) void gemm8p_sk(const u16* __restrict__ A, const u16* __restrict__ Bt,
                                                    u16* __restrict__ part,
                                                    int M, int N, int Kstride, int Klen){
  extern __shared__ u16 lds[];
  const int tid = threadIdx.x;
  const int lane = tid & 63, lr = lane >> 4, lc = lane & 15;
  const int wid = tid >> 6, wr = wid >> 2, wc = wid & 3;
  int bx = blockIdx.x, by = blockIdx.y;
  xcd_swz(bx, by);
  const int sk = blockIdx.z;
  const size_t koff = (size_t)sk * Klen;
  const int m0 = by * 256, n0 = bx * 256;
  const int NT = Klen >> 5;
  const int slot8 = ((lr ^ (lc & 3)) << 3);

  f32x4 acc[8][4];
  #pragma unroll
  for (int i = 0; i < 8; i++)
    #pragma unroll
    for (int j = 0; j < 4; j++) acc[i][j] = (f32x4){0.f,0.f,0.f,0.f};

  const int srow = tid >> 2;
  const int scg  = (tid & 3) ^ (srow & 3);

  auto stage = [&](int t, int buf, int rsel){
    int row = ((rsel & 1) << 7) + srow;
    const u16* src = ((rsel < 2) ? A + (size_t)(m0 + row) * Kstride
                                 : Bt + (size_t)(n0 + row) * Kstride) + koff + t * 32 + scg * 8;
    u16* dst = lds + buf * 16384 + ((rsel & 2) << 12) + ((rsel & 1) << 12) + tid * 8;
    gload16(src, dst);
  };
  auto ldA = [&](int buf, int mi) -> bf16x8 {
    int ra = wr * 128 + mi * 16 + lc;
    return *(const bf16x8*)&lds[buf * 16384 + ra * 32 + slot8];
  };
  auto ldB = [&](int buf, int ni) -> bf16x8 {
    int rb = wc * 64 + ni * 16 + lc;
    return *(const bf16x8*)&lds[buf * 16384 + 8192 + rb * 32 + slot8];
  };

  #pragma unroll
  for (int rs = 0; rs < 4; rs++) stage(0, 0, rs);
  #pragma unroll
  for (int rs = 0; rs < 4; rs++) stage(1, 1, rs);
  asm volatile("s_waitcnt vmcnt(4)" ::: "memory");
  __builtin_amdgcn_s_barrier();

  int buf = 0;
  for (int t = 0; t < NT; t++){
    int sbuf = buf + 2; if (sbuf >= 3) sbuf -= 3;
    bool ds = (t + 2 < NT);
    bf16x8 a[4], b[4];
    #pragma unroll
    for (int mi = 0; mi < 4; mi++) a[mi] = ldA(buf, mi);
    #pragma unroll
    for (int ni = 0; ni < 4; ni++) b[ni] = ldB(buf, ni);
    if (ds){ stage(t + 2, sbuf, 0); stage(t + 2, sbuf, 1); }
    __builtin_amdgcn_s_barrier();
    __builtin_amdgcn_s_setprio(1);
    #pragma unroll
    for (int mi = 0; mi < 4; mi++)
      #pragma unroll
      for (int ni = 0; ni < 4; ni++)
        acc[mi][ni] = __builtin_amdgcn_mfma_f32_16x16x32_bf16(a[mi], b[ni], acc[mi][ni], 0, 0, 0);
    __builtin_amdgcn_s_setprio(0);
    __builtin_amdgcn_s_barrier();
    #pragma unroll
    for (int mi = 0; mi < 4; mi++) a[mi] = ldA(buf, mi + 4);
    if (ds){ stage(t + 2, sbuf, 2); stage(t + 2, sbuf, 3); }
    __builtin_amdgcn_s_barrier();
    __builtin_amdgcn_s_setprio(1);
    #pragma unroll
    for (int mi = 0; mi < 4; mi++)
      #pragma unroll
      for (int ni = 0; ni < 4; ni++)
        acc[mi + 4][ni] = __builtin_amdgcn_mfma_f32_16x16x32_bf16(a[mi], b[ni], acc[mi + 4][ni], 0, 0, 0);
    __builtin_amdgcn_s_setprio(0);
    if (t + 2 < NT)      { asm volatile("s_waitcnt vmcnt(4)" ::: "memory"); }
    else if (t + 1 < NT) { asm volatile("s_waitcnt vmcnt(0)" ::: "memory"); }
    __builtin_amdgcn_s_barrier();
    buf++; if (buf == 3) buf = 0;
  }

  u16* po = part + (size_t)sk * M * N;
  #pragma unroll
  for (int mi = 0; mi < 8; mi++){
    #pragma unroll
    for (int ni = 0; ni < 4; ni++){
      int col = n0 + wc * 64 + ni * 16 + lc;
      #pragma unroll
      for (int r = 0; r < 4; r++){
        int row = m0 + wr * 128 + mi * 16 + lr * 4 + r;
        po[(size_t)row * N + col] = f2bf(acc[mi][ni][r]);
      }
    }
  }
}

// ---- O-proj merge + residual + fused RMSNorm2: writes x2 (fp32) AND h2 (bf16) ----
// block = 256 threads * 8 elems = 2048 = 2 rows of 1024. waves 0,1 -> row0; 2,3 -> row1.
__global__ __launch_bounds__(256) void skmerge_rms(const u16* __restrict__ part, const float* __restrict__ resid,
                                                   const float* __restrict__ g2, float* __restrict__ x2,
                                                   u16* __restrict__ h2){
  size_t i = ((size_t)blockIdx.x * 256 + threadIdx.x) * 8;
  int col = (int)(i & (DIMD - 1));
  const size_t MN = (size_t)4096 * DIMD;
  short8 a0 = *(const short8*)&part[i];
  short8 a1 = *(const short8*)&part[MN + i];
  short8 a2 = *(const short8*)&part[2 * MN + i];
  short8 a3 = *(const short8*)&part[3 * MN + i];
  float4 xa = *(const float4*)&resid[i];
  float4 xb = *(const float4*)&resid[i + 4];
  float o[8];
  #pragma unroll
  for (int j = 0; j < 8; j++)
    o[j] = (bf2f((u16)a0[j]) + bf2f((u16)a1[j])) + (bf2f((u16)a2[j]) + bf2f((u16)a3[j]));
  o[0] += xa.x; o[1] += xa.y; o[2] += xa.z; o[3] += xa.w;
  o[4] += xb.x; o[5] += xb.y; o[6] += xb.z; o[7] += xb.w;
  *(float4*)&x2[i]     = (float4){o[0], o[1], o[2], o[3]};
  *(float4*)&x2[i + 4] = (float4){o[4], o[5], o[6], o[7]};

  // fused RMSNorm over each 1024-row
  float ss = 0.f;
  #pragma unroll
  for (int j = 0; j < 8; j++) ss += o[j] * o[j];
  #pragma unroll
  for (int off = 32; off > 0; off >>= 1) ss += __shfl_down(ss, off);
  __shared__ float red[4];
  if ((threadIdx.x & 63) == 0) red[threadIdx.x >> 6] = ss;
  __syncthreads();
  float tot = (threadIdx.x < 128) ? (red[0] + red[1]) : (red[2] + red[3]);
  float rs = rsqrtf(tot / (float)DIMD + 1e-6f);
  float4 ga = *(const float4*)&g2[col];
  float4 gb = *(const float4*)&g2[col + 4];
  ushort4 h0, h1;
  h0.x = f2bf(o[0] * rs * ga.x); h0.y = f2bf(o[1] * rs * ga.y);
  h0.z = f2bf(o[2] * rs * ga.z); h0.w = f2bf(o[3] * rs * ga.w);
  h1.x = f2bf(o[4] * rs * gb.x); h1.y = f2bf(o[5] * rs * gb.y);
  h1.z = f2bf(o[6] * rs * gb.z); h1.w = f2bf(o[7] * rs * gb.w);
  *(ushort4*)&h2[i]     = h0;
  *(ushort4*)&h2[i + 4] = h1;
}

// merge 4 bf16 partials + resid + bias -> fp32 out  (FFN2)
__global__ __launch_bounds__(256) void ffn2_merge(const u16* __restrict__ part, const float* __restrict__ x2,
                                                  const float* __restrict__ b2, float* __restrict__ out){
  size_t i = ((size_t)blockIdx.x * 256 + threadIdx.x) * 8;
  int col = (int)(i & (DIMD - 1));
  const size_t MN = (size_t)4096 * DIMD;
  short8 a0 = *(const short8*)&part[i];
  short8 a1 = *(const short8*)&part[MN + i];
  short8 a2 = *(const short8*)&part[2 * MN + i];
  short8 a3 = *(const short8*)&part[3 * MN + i];
  float r[8];
  #pragma unroll
  for (int j = 0; j < 8; j++)
    r[j] = (bf2f((u16)a0[j]) + bf2f((u16)a1[j])) + (bf2f((u16)a2[j]) + bf2f((u16)a3[j]));
  float4 xa = *(const float4*)&x2[i];
  float4 xb = *(const float4*)&x2[i + 4];
  float4 ba = *(const float4*)&b2[col];
  float4 bb = *(const float4*)&b2[col + 4];
  float4 o0 = {r[0] + xa.x + ba.x, r[1] + xa.y + ba.y, r[2] + xa.z + ba.z, r[3] + xa.w + ba.w};
  float4 o1 = {r[4] + xb.x + bb.x, r[5] + xb.y + bb.y, r[6] + xb.z + bb.z, r[7] + xb.w + bb.w};
  *(float4*)&out[i] = o0;
  *(float4*)&out[i + 4] = o1;
}

// ---------------- flash attention: 32x32 swapped QK^T (proven 333us config) ----------------
__global__ __launch_bounds__(256) void attn_part(const u16* __restrict__ qkv, const u16* __restrict__ vt,
                                                 const float* __restrict__ bias,
                                                 const unsigned char* __restrict__ mask,
                                                 u16* __restrict__ Opart, float* __restrict__ mp, float* __restrict__ lp){
  __shared__ u16 Ks [64 * 64];   // [key][d]   XOR-swizzled
  __shared__ u16 Vts[64 * 64];   // [d][key]   XOR-swizzled
  __shared__ u16 Ps [4 * 32 * 72]; // per-wave [q=32][key=64 (+pad)]

  const int tid = threadIdx.x;
  const int lane = tid & 63, hi = lane >> 5, lq = lane & 31;
  const int wq = tid >> 6;
  const int b  = blockIdx.x & 1;
  const int qb = blockIdx.x >> 1;
  const int h  = blockIdx.y;
  const int sp = blockIdx.z;
  const int qw = qb * 128 + wq * 32;
  const int kv_lo = sp * KVSPAN, kv_hi = kv_lo + KVSPAN;

  char* kls = (char*)Ks;
  char* vls = (char*)Vts;
  u16*  psw = Ps + wq * 32 * 72;

  bf16x8 qf[4];
  {
    const u16* qp = qkv + ((size_t)(b * SSEQ + qw + lq)) * 3072 + h * HD + hi * 8;
    #pragma unroll
    for (int dstep = 0; dstep < 4; dstep++) qf[dstep] = *(const bf16x8*)(qp + dstep * 16);
  }

  const u16* kbase = qkv + (size_t)b * SSEQ * 3072 + 1024 + h * HD;
  const u16* vbase = vt + (size_t)(b * NHEAD + h) * HD * SSEQ;
  const int c0 = tid, c1 = tid + 256;
  auto kaddr = [&](int kv0, int c){ return kbase + (size_t)(kv0 + (c >> 3)) * 3072 + (c & 7) * 8; };
  auto vaddr = [&](int kv0, int c){ return vbase + (size_t)(c >> 3) * SSEQ + kv0 + (c & 7) * 8; };
  auto sstore = [&](char* base, int c, short8 v){
    int byte = (c >> 3) * 128 + (c & 7) * 16;
    byte ^= ((c >> 3) & 7) << 4;
    *(short8*)(base + byte) = v;
  };

  const float* brow = bias + ((size_t)h * SSEQ + (qw + lq)) * SSEQ;
  const unsigned char* mbase = mask + b * SSEQ;

  short8 kr0 = *(const short8*)kaddr(kv_lo, c0);
  short8 kr1 = *(const short8*)kaddr(kv_lo, c1);
  short8 vr0 = *(const short8*)vaddr(kv_lo, c0);
  short8 vr1 = *(const short8*)vaddr(kv_lo, c1);

  float mrow = NEGF, lsum = 0.f;
  f32x16 oacc[2];
  #pragma unroll
  for (int g = 0; g < 2; g++)
    #pragma unroll
    for (int r = 0; r < 16; r++) oacc[g][r] = 0.f;

  for (int kv0 = kv_lo; kv0 < kv_hi; kv0 += 64){
    float4 bv[8]; unsigned mk[8];
    #pragma unroll
    for (int kg = 0; kg < 2; kg++)
      #pragma unroll
      for (int rq = 0; rq < 4; rq++){
        int base = kv0 + kg * 32 + 8 * rq + 4 * hi;
        bv[kg*4+rq] = *(const float4*)&brow[base];
        mk[kg*4+rq] = *(const unsigned*)&mbase[base];
      }

    __syncthreads();
    sstore(kls, c0, kr0); sstore(kls, c1, kr1);
    sstore(vls, c0, vr0); sstore(vls, c1, vr1);
    __syncthreads();

    {
      int nxt = (kv0 + 64 < kv_hi) ? kv0 + 64 : kv_lo;
      kr0 = *(const short8*)kaddr(nxt, c0);
      kr1 = *(const short8*)kaddr(nxt, c1);
      vr0 = *(const short8*)vaddr(nxt, c0);
      vr1 = *(const short8*)vaddr(nxt, c1);
    }

    f32x16 acc[2];
    #pragma unroll
    for (int g = 0; g < 2; g++)
      #pragma unroll
      for (int r = 0; r < 16; r++) acc[g][r] = 0.f;
    __builtin_amdgcn_s_setprio(1);
    #pragma unroll
    for (int kg = 0; kg < 2; kg++){
      int row = kg * 32 + lq;
      #pragma unroll
      for (int dstep = 0; dstep < 4; dstep++){
        int byte = row * 128 + dstep * 32 + hi * 16;
        byte ^= (row & 7) << 4;
        bf16x8 kf = *(const bf16x8*)(kls + byte);
        acc[kg] = __builtin_amdgcn_mfma_f32_32x32x16_bf16(kf, qf[dstep], acc[kg], 0, 0, 0);
      }
    }
    __builtin_amdgcn_s_setprio(0);

    float p[2][16];
    float tm = NEGF;
    #pragma unroll
    for (int kg = 0; kg < 2; kg++)
      #pragma unroll
      for (int r = 0; r < 16; r++){
        int g = kg * 4 + (r >> 2);
        bool m = ((mk[g] >> (8 * (r & 3))) & 0xffu) != 0;
        float v = acc[kg][r] * 0.125f + ((const float*)&bv[g])[r & 3];
        v = m ? NEGF : v;
        p[kg][r] = v;
        tm = fmaxf(tm, v);
      }
    tm = fmaxf(tm, __shfl_xor(tm, 32));

    if (__any(tm > mrow + 5.f)){
      float mnew = fmaxf(mrow, tm);
      float corr = __expf(mrow - mnew);
      lsum *= corr;
      mrow = mnew;
      #pragma unroll
      for (int r = 0; r < 16; r++){
        float cr = __shfl(corr, (r & 3) + 8 * (r >> 2) + 4 * hi);
        oacc[0][r] *= cr;
        oacc[1][r] *= cr;
      }
    }

    float psum = 0.f;
    #pragma unroll
    for (int kg = 0; kg < 2; kg++)
      #pragma unroll
      for (int r = 0; r < 16; r++){
        float sv = p[kg][r];
        float e = (sv < -1e30f) ? 0.f : __expf(sv - mrow);
        p[kg][r] = e;
        psum += e;
      }
    psum += __shfl_xor(psum, 32);
    lsum += psum;

    #pragma unroll
    for (int kg = 0; kg < 2; kg++)
      #pragma unroll
      for (int rq = 0; rq < 4; rq++){
        short4v pk;
        #pragma unroll
        for (int t = 0; t < 4; t++)
          pk[t] = (short)(__float_as_uint(p[kg][rq * 4 + t]) >> 16);
        *(short4v*)&psw[lq * 72 + kg * 32 + 8 * rq + 4 * hi] = pk;
      }

    __builtin_amdgcn_s_setprio(1);
    #pragma unroll
    for (int ks = 0; ks < 4; ks++){
      bf16x8 pa = *(const bf16x8*)&psw[lq * 72 + ks * 16 + hi * 8];
      #pragma unroll
      for (int dgrp = 0; dgrp < 2; dgrp++){
        int row = dgrp * 32 + lq;
        int byte = row * 128 + ks * 32 + hi * 16;
        byte ^= (row & 7) << 4;
        bf16x8 vf = *(const bf16x8*)(vls + byte);
        oacc[dgrp] = __builtin_amdgcn_mfma_f32_32x32x16_bf16(pa, vf, oacc[dgrp], 0, 0, 0);
      }
    }
    __builtin_amdgcn_s_setprio(0);
  }

  if (lane < 32){
    int ridx = (b * NHEAD + h) * SSEQ + qw + lq;
    mp[sp * NROWS + ridx] = mrow;
    lp[sp * NROWS + ridx] = lsum;
  }
  #pragma unroll
  for (int r = 0; r < 16; r++){
    int qloc = (r & 3) + 8 * (r >> 2) + 4 * hi;
    int ridx = (b * NHEAD + h) * SSEQ + qw + qloc;
    size_t o = ((size_t)(sp * NROWS + ridx)) * HD;
    Opart[o + lq]      = f2bf(oacc[0][r]);
    Opart[o + 32 + lq] = f2bf(oacc[1][r]);
  }
}

// ---------------- split-KV merge ----------------
__global__ __launch_bounds__(256) void attn_merge(const u16* __restrict__ Opart, const float* __restrict__ mp,
                                                  const float* __restrict__ lp, u16* __restrict__ attn){
  int row = blockIdx.x * 16 + (threadIdx.x >> 4);
  int tx = threadIdx.x & 15;
  float ms[NSPLIT], ls[NSPLIT];
  float m = NEGF;
  #pragma unroll
  for (int sp = 0; sp < NSPLIT; sp++){
    ms[sp] = mp[sp * NROWS + row];
    ls[sp] = lp[sp * NROWS + row];
    if (ls[sp] > 0.f) m = fmaxf(m, ms[sp]);
  }
  float acc0 = 0.f, acc1 = 0.f, acc2 = 0.f, acc3 = 0.f, ltot = 0.f;
  #pragma unroll
  for (int sp = 0; sp < NSPLIT; sp++){
    float e = (ls[sp] > 0.f) ? __expf(ms[sp] - m) : 0.f;
    ltot += ls[sp] * e;
    ushort4 o4 = *(const ushort4*)&Opart[((size_t)(sp * NROWS + row)) * HD + tx*4];
    acc0 += e * bf2f(o4.x);
    acc1 += e * bf2f(o4.y);
    acc2 += e * bf2f(o4.z);
    acc3 += e * bf2f(o4.w);
  }
  float inv = ltot > 0.f ? 1.f / ltot : 0.f;
  int b = row >> 15, h = (row >> 11) & 15, q = row & 2047;
  ushort4 r4;
  r4.x = f2bf(acc0 * inv);
  r4.y = f2bf(acc1 * inv);
  r4.z = f2bf(acc2 * inv);
  r4.w = f2bf(acc3 * inv);
  *(ushort4*)&attn[((size_t)(b * SSEQ + q)) * DIMD + h * HD + tx*4] = r4;
}

// ---------------- launch ----------------
extern "C" void kernel_launch(void* const* d_in, const int* in_sizes, int n_in,
                              void* d_out, int out_size, void* d_ws, size_t ws_size,
                              hipStream_t stream){
  const float* x    = (const float*)d_in[0];
  const unsigned char* mask = (const unsigned char*)d_in[1];
  const float* bias = (const float*)d_in[2];
  const float* Wq   = (const float*)d_in[3];
  const float* Wk   = (const float*)d_in[4];
  const float* Wv   = (const float*)d_in[5];
  const float* Wo   = (const float*)d_in[6];
  const float* W1   = (const float*)d_in[7];
  const float* b1   = (const float*)d_in[8];
  const float* W2   = (const float*)d_in[9];
  const float* b2   = (const float*)d_in[10];
  const float* g1   = (const float*)d_in[11];
  const float* g2   = (const float*)d_in[12];
  float* out = (float*)d_out;

  char* ws = (char*)d_ws;
  size_t off = 0;
  auto take = [&](size_t bytes) -> char* {
    char* p = ws + off;
    off = (off + bytes + 255) & ~(size_t)255;
    return p;
  };
  u16*  wqkv_t = (u16*) take((size_t)3072*1024*2);
  u16*  wo_t   = (u16*) take((size_t)1024*1024*2);
  u16*  w1_t   = (u16*) take((size_t)4096*1024*2);
  u16*  w2_t   = (u16*) take((size_t)1024*4096*2);
  u16*  hbuf   = (u16*) take((size_t)4096*1024*2);
  u16*  qkv    = (u16*) take((size_t)4096*3072*2);
  u16*  attn   = (u16*) take((size_t)4096*1024*2);
  float* x2    = (float*)take((size_t)4096*1024*4);
  u16*  h2     = (u16*) take((size_t)4096*1024*2);
  u16*  fbuf   = (u16*) take((size_t)4096*4096*2);
  unsigned char* nmask = (unsigned char*)take(BB*SSEQ);
  float* mpbuf = (float*)take((size_t)NSPLIT*NROWS*4);
  float* lpbuf = (float*)take((size_t)NSPLIT*NROWS*4);
  u16*  fp2    = (u16*) take((size_t)4*4096*1024*2);   // split-K partials (O-proj, then FFN2)
  u16* Opart = fbuf;   // alias: consumed by attn_merge before FFN1 writes fbuf
  u16* vt_g  = hbuf;   // alias: hbuf dead after QKV GEMM

  hipFuncSetAttribute(reinterpret_cast<const void*>(gemm8p<0>),
                      hipFuncAttributeMaxDynamicSharedMemorySize, 98304);
  hipFuncSetAttribute(reinterpret_cast<const void*>(gemm8p<2>),
                      hipFuncAttributeMaxDynamicSharedMemorySize, 98304);
  hipFuncSetAttribute(reinterpret_cast<const void*>(gemm8p_sk),
                      hipFuncAttributeMaxDynamicSharedMemorySize, 98304);

  normalize_mask<<<1, 1024, 0, stream>>>(mask, nmask);

  dim3 tb(32, 8);
  transpose4_to_bf16<<<dim3(32, 32, 4), tb, 0, stream>>>(Wq, Wk, Wv, Wo, wqkv_t, wo_t);
  transpose_to_bf16<<<dim3(128, 32), tb, 0, stream>>>(W1, w1_t, 1024, 4096);
  transpose_to_bf16<<<dim3(32, 128), tb, 0, stream>>>(W2, w2_t, 4096, 1024);

  rmsnorm_k<<<4096, 256, 0, stream>>>(x, g1, hbuf, DIMD);

  gemm8p<0><<<dim3(3072/256, 4096/256), 512, 98304, stream>>>(hbuf, wqkv_t, qkv, nullptr, 4096, 3072, 1024);

  vtrans<<<dim3(SSEQ/32, 2, BB*NHEAD), tb, 0, stream>>>(qkv, vt_g);

  attn_part<<<dim3(2*SSEQ/128, NHEAD, NSPLIT), 256, 0, stream>>>(qkv, vt_g, bias, nmask, Opart, mpbuf, lpbuf);
  attn_merge<<<dim3(NROWS/16), 256, 0, stream>>>(Opart, mpbuf, lpbuf, attn);

  // O-proj: split-K 256^2 GEMM -> partials; merge + residual + fused RMSNorm2
  gemm8p_sk<<<dim3(1024/256, 4096/256, 4), 512, 98304, stream>>>(attn, wo_t, fp2, 4096, 1024, 1024, 256);
  skmerge_rms<<<dim3(4096*1024/2048), 256, 0, stream>>>(fp2, x, g2, x2, h2);

  gemm8p<2><<<dim3(4096/256, 4096/256), 512, 98304, stream>>>(h2, w1_t, fbuf, b1, 4096, 4096, 1024);

  gemm8p_sk<<<dim3(1024/256, 4096/256, 4), 512, 98304, stream>>>(fbuf, w2_t, fp2, 4096, 1024, 4096, 1024);
  ffn2_merge<<<dim3(4096*1024/2048), 256, 0, stream>>>(fp2, x2, b2, out);
}